// Round 2
// baseline (4456.721 us; speedup 1.0000x reference)
//
#include <hip/hip_runtime.h>

#define N_NODES 50000
#define N_EDGES 800000
#define N_GRAPHS 256
#define N_LAYERS 3
#define DIM 300
#define NFEAT 128
#define EFEAT 16
#define OUTD 128
#define BN_EPS 1e-5f

typedef __attribute__((ext_vector_type(8))) short bfrag8;   // 8 bf16 = 4 VGPR (MFMA A/B operand)
typedef __attribute__((ext_vector_type(4))) float facc4;    // MFMA C/D
typedef __attribute__((ext_vector_type(4))) unsigned short us4;
typedef __attribute__((ext_vector_type(8))) unsigned short us8;

// ---------------- bf16 helpers (RNE) + hi/lo split ----------------
__device__ __forceinline__ unsigned short f2bf(float f) {
    unsigned u = __float_as_uint(f);
    unsigned r = ((u >> 16) & 1u) + 0x7fffu;
    return (unsigned short)((u + r) >> 16);
}
__device__ __forceinline__ float bf2f(unsigned short h) {
    return __uint_as_float(((unsigned)h) << 16);
}
__device__ __forceinline__ void split2(float v, unsigned short& h, unsigned short& l) {
    h = f2bf(v);
    l = f2bf(v - bf2f(h));
}

// async global->LDS, 16B per lane. LDS dest = uniform base + lane*16 (HW rule).
__device__ __forceinline__ void load_lds16(const void* gsrc, void* ldsdst) {
    __builtin_amdgcn_global_load_lds(
        (const __attribute__((address_space(1))) unsigned int*)gsrc,
        (__attribute__((address_space(3))) unsigned int*)ldsdst,
        16, 0, 0);
}

#define MFMA16(a, b, c) __builtin_amdgcn_mfma_f32_16x16x32_bf16(a, b, c, 0, 0, 0)

// ---------------------------------------------------------------------------
// fp32 -> bf16 (hi only), vectorized
// ---------------------------------------------------------------------------
__global__ __launch_bounds__(256) void tobf4(
    const float* __restrict__ x, unsigned short* __restrict__ H, int n4)
{
    int i = blockIdx.x * 256 + threadIdx.x;
    if (i >= n4) return;
    float4 v = ((const float4*)x)[i];
    us4 h;
    h.x = f2bf(v.x); h.y = f2bf(v.y); h.z = f2bf(v.z); h.w = f2bf(v.w);
    ((us4*)H)[i] = h;
}

// ---------------------------------------------------------------------------
// weight conversion: W fp32 [K][N] -> transposed padded hi/lo planes [Np][Kp]
// ---------------------------------------------------------------------------
__global__ __launch_bounds__(256) void conv_wt(
    const float* __restrict__ W, unsigned short* __restrict__ H,
    unsigned short* __restrict__ L, int K, int N, int Kp, int Np)
{
    int idx = blockIdx.x * 256 + threadIdx.x;
    if (idx >= Np * Kp) return;
    int n = idx / Kp;
    int k = idx - n * Kp;
    float v = (n < N && k < K) ? W[(size_t)k * N + n] : 0.f;
    unsigned short h, l;
    split2(v, h, l);
    H[idx] = h;
    L[idx] = l;
}

// ---------------------------------------------------------------------------
// Edge-weight conversion into MFMA B-fragment order for the gather kernel.
// Layout: entry t = c*128 + p*64 + lane (c=dim-chunk 0..18, p=hi/lo plane,
// lane=MFMA lane). Lane holds col n = lane&15 (dim within chunk), k-octet
// g = lane>>4 (k = 8g+i). What k: k<16 -> eW[k][dim]; k==16 -> eb[dim] (bias
// folded as a 17th "constant-1" edge feature); k>16 -> 0.
// ---------------------------------------------------------------------------
__global__ __launch_bounds__(256) void conv_ew(
    const float* __restrict__ eW, const float* __restrict__ eb,
    unsigned short* __restrict__ out)
{
    int t = blockIdx.x * 256 + threadIdx.x;
    if (t >= 2432) return;            // 19 chunks * 2 planes * 64 lanes
    int c = t >> 7;
    int p = (t >> 6) & 1;
    int lane = t & 63;
    int n = lane & 15, g = lane >> 4;
    int col = c * 16 + n;
    us8 o;
#pragma unroll
    for (int i = 0; i < 8; ++i) {
        int k = 8 * g + i;
        float v = 0.f;
        if (col < DIM) {
            if (k < EFEAT) v = eW[k * DIM + col];
            else if (k == EFEAT) v = eb[col];
        }
        unsigned short h, l;
        split2(v, h, l);
        o[i] = p ? l : h;
    }
    *(us8*)&out[(size_t)t * 8] = o;
}

__global__ __launch_bounds__(256) void fill_dummy(float* __restrict__ d)
{
    int i = blockIdx.x * 256 + threadIdx.x;
    if (i < 320) d[i] = -1e30f;
}

// ---------------------------------------------------------------------------
// bf16 MFMA GEMM: A plain bf16 [M][Kp]; B transposed hi/lo planes [Np][Kp].
// acc = Ah*Bh + Ah*Bl (2 MFMA/tile). Block 128x128, BK=32, 4 waves 2x2.
// GRID: blockIdx.x = N-block (fast-varying) so consecutive blocks share the
// same A row-tile -> A L2 reuse across column blocks. blockIdx.y = M-block.
// LDS 24KB: A | Bh | Bl. Optional column-stat epilogue (BN).
// ---------------------------------------------------------------------------
__global__ __launch_bounds__(256, 2) void gemm_pp(
    const unsigned short* __restrict__ Ah,
    const unsigned short* __restrict__ Bth, const unsigned short* __restrict__ Btl,
    const float* __restrict__ bias, float* __restrict__ C,
    int M, int N, int Kp, float* __restrict__ stats)
{
    __shared__ unsigned short lds[12288];   // 24 KB
    const int tid = threadIdx.x;
    const int lane = tid & 63;
    const int w = tid >> 6;
    const int m0 = blockIdx.y * 128;
    const int n0 = blockIdx.x * 128;
    const int wm = (w & 1) * 64;
    const int wn = (w >> 1) * 64;

    const int srow = lane >> 2;
    const int scol = (lane & 3) * 8;

    const unsigned short* gp[6];
    unsigned loff[6];
#pragma unroll
    for (int i = 0; i < 6; ++i) {
        int c = w * 6 + i;
        const unsigned short* pl = (c < 8) ? Ah : (c < 16) ? Bth : Btl;
        int rowg;
        if (c < 8) {
            rowg = m0 + (c & 7) * 16 + srow;
            rowg = min(rowg, M - 1);
        } else {
            rowg = n0 + (c & 7) * 16 + srow;
        }
        gp[i] = pl + (size_t)rowg * Kp + scol;
        loff[i] = c * 512;
    }

    facc4 acc[4][4];
    facc4 zero = {0.f, 0.f, 0.f, 0.f};
#pragma unroll
    for (int i = 0; i < 4; ++i)
#pragma unroll
        for (int j = 0; j < 4; ++j) acc[i][j] = zero;

    const int fr = lane & 15;
    const int fq = (lane >> 4) * 8;

    for (int k0 = 0; k0 < Kp; k0 += 32) {
#pragma unroll
        for (int i = 0; i < 6; ++i) {
            load_lds16(gp[i], &lds[loff[i]]);
            gp[i] += 32;
        }
        __syncthreads();

        bfrag8 ah[4], bh[4], bl[4];
#pragma unroll
        for (int t = 0; t < 4; ++t) {
            int ar = wm + t * 16 + fr;
            ah[t] = *(const bfrag8*)&lds[ar * 32 + fq];
            int br = wn + t * 16 + fr;
            bh[t] = *(const bfrag8*)&lds[4096 + br * 32 + fq];
            bl[t] = *(const bfrag8*)&lds[8192 + br * 32 + fq];
        }
#pragma unroll
        for (int i = 0; i < 4; ++i)
#pragma unroll
            for (int j = 0; j < 4; ++j) {
                acc[i][j] = MFMA16(ah[i], bh[j], acc[i][j]);
                acc[i][j] = MFMA16(ah[i], bl[j], acc[i][j]);
            }
        __syncthreads();
    }

    // epilogue: C/D layout col=lane&15, row=(lane>>4)*4+reg
#pragma unroll
    for (int i = 0; i < 4; ++i)
#pragma unroll
        for (int j = 0; j < 4; ++j) {
            int col = n0 + wn + j * 16 + (lane & 15);
            if (col >= N) continue;
            float bv = bias[col];
#pragma unroll
            for (int r = 0; r < 4; ++r) {
                int row = m0 + wm + i * 16 + (lane >> 4) * 4 + r;
                if (row < M)
                    C[(size_t)row * N + col] = acc[i][j][r] + bv;
            }
        }

    if (stats != nullptr) {
#pragma unroll
        for (int j = 0; j < 4; ++j) {
            int col = n0 + wn + j * 16 + (lane & 15);
            float cs = 0.f, cq = 0.f;
            if (col < N) {
                float bv = bias[col];
#pragma unroll
                for (int i = 0; i < 4; ++i)
#pragma unroll
                    for (int r = 0; r < 4; ++r) {
                        int row = m0 + wm + i * 16 + (lane >> 4) * 4 + r;
                        if (row < M) {
                            float y = acc[i][j][r] + bv;
                            cs += y;
                            cq = fmaf(y, y, cq);
                        }
                    }
            }
            cs += __shfl_xor(cs, 16, 64); cq += __shfl_xor(cq, 16, 64);
            cs += __shfl_xor(cs, 32, 64); cq += __shfl_xor(cq, 32, 64);
            if ((lane >> 4) == 0 && col < N) {
                atomicAdd(&stats[col], cs);
                atomicAdd(&stats[N + col], cq);
            }
        }
    }
}

// ---------------------------------------------------------------------------
// bf16 MFMA GEMM, A fp32 with fused BN-affine+ReLU applied during staging
// (abn = [a K | b K], y = relu(x*a+b)) -> bf16 hi only. Grid transposed as
// gemm_pp (x=N-block) for A L2 reuse. Column-stat epilogue for BN2.
// ---------------------------------------------------------------------------
__global__ __launch_bounds__(256, 2) void gemm_af(
    const float* __restrict__ A, const unsigned short* __restrict__ Bth,
    const unsigned short* __restrict__ Btl, const float* __restrict__ bias,
    float* __restrict__ C, int M, int N, int K, int Kp,
    const float* __restrict__ abn, float* __restrict__ stats)
{
    __shared__ unsigned short lds[12288];
    const int tid = threadIdx.x;
    const int lane = tid & 63;
    const int w = tid >> 6;
    const int m0 = blockIdx.y * 128;
    const int n0 = blockIdx.x * 128;
    const int wm = (w & 1) * 64;
    const int wn = (w >> 1) * 64;

    const int srow = lane >> 2;
    const int scol = (lane & 3) * 8;

    const unsigned short* gpb[4];
    unsigned loffb[4];
#pragma unroll
    for (int i = 0; i < 4; ++i) {
        int c = w * 4 + i;
        const unsigned short* pl = (c < 8) ? Bth : Btl;
        int rowg = n0 + (c & 7) * 16 + srow;
        gpb[i] = pl + (size_t)rowg * Kp + scol;
        loffb[i] = 4096 + c * 512;
    }

    facc4 acc[4][4];
    facc4 zero = {0.f, 0.f, 0.f, 0.f};
#pragma unroll
    for (int i = 0; i < 4; ++i)
#pragma unroll
        for (int j = 0; j < 4; ++j) acc[i][j] = zero;

    const int fr = lane & 15;
    const int fq = (lane >> 4) * 8;

    for (int k0 = 0; k0 < Kp; k0 += 32) {
#pragma unroll
        for (int i = 0; i < 4; ++i) {
            load_lds16(gpb[i], &lds[loffb[i]]);
            gpb[i] += 32;
        }
        // A fp32 -> BN affine + relu -> bf16 into LDS (128 rows x 32 k)
#pragma unroll
        for (int i = 0; i < 4; ++i) {
            int idx = tid + i * 256;
            int row = idx >> 3;
            int q4 = idx & 7;
            int rg = min(m0 + row, M - 1);
            int kk = k0 + q4 * 4;
            us4 h;
            if (kk < K) {
                float4 v = *(const float4*)&A[(size_t)rg * K + kk];
                float4 sa = *(const float4*)&abn[kk];
                float4 sb = *(const float4*)&abn[K + kk];
                h.x = f2bf(fmaxf(fmaf(v.x, sa.x, sb.x), 0.f));
                h.y = f2bf(fmaxf(fmaf(v.y, sa.y, sb.y), 0.f));
                h.z = f2bf(fmaxf(fmaf(v.z, sa.z, sb.z), 0.f));
                h.w = f2bf(fmaxf(fmaf(v.w, sa.w, sb.w), 0.f));
            } else {
                h.x = 0; h.y = 0; h.z = 0; h.w = 0;
            }
            *(us4*)&lds[row * 32 + q4 * 4] = h;
        }
        __syncthreads();

        bfrag8 ah[4], bh[4], bl[4];
#pragma unroll
        for (int t = 0; t < 4; ++t) {
            int ar = wm + t * 16 + fr;
            ah[t] = *(const bfrag8*)&lds[ar * 32 + fq];
            int br = wn + t * 16 + fr;
            bh[t] = *(const bfrag8*)&lds[4096 + br * 32 + fq];
            bl[t] = *(const bfrag8*)&lds[8192 + br * 32 + fq];
        }
#pragma unroll
        for (int i = 0; i < 4; ++i)
#pragma unroll
            for (int j = 0; j < 4; ++j) {
                acc[i][j] = MFMA16(ah[i], bh[j], acc[i][j]);
                acc[i][j] = MFMA16(ah[i], bl[j], acc[i][j]);
            }
        __syncthreads();
    }

#pragma unroll
    for (int i = 0; i < 4; ++i)
#pragma unroll
        for (int j = 0; j < 4; ++j) {
            int col = n0 + wn + j * 16 + (lane & 15);
            if (col >= N) continue;
            float bv = bias[col];
#pragma unroll
            for (int r = 0; r < 4; ++r) {
                int row = m0 + wm + i * 16 + (lane >> 4) * 4 + r;
                if (row < M)
                    C[(size_t)row * N + col] = acc[i][j][r] + bv;
            }
        }

    if (stats != nullptr) {
#pragma unroll
        for (int j = 0; j < 4; ++j) {
            int col = n0 + wn + j * 16 + (lane & 15);
            float cs = 0.f, cq = 0.f;
            if (col < N) {
                float bv = bias[col];
#pragma unroll
                for (int i = 0; i < 4; ++i)
#pragma unroll
                    for (int r = 0; r < 4; ++r) {
                        int row = m0 + wm + i * 16 + (lane >> 4) * 4 + r;
                        if (row < M) {
                            float y = acc[i][j][r] + bv;
                            cs += y;
                            cq = fmaf(y, y, cq);
                        }
                    }
            }
            cs += __shfl_xor(cs, 16, 64); cq += __shfl_xor(cq, 16, 64);
            cs += __shfl_xor(cs, 32, 64); cq += __shfl_xor(cq, 32, 64);
            if ((lane >> 4) == 0 && col < N) {
                atomicAdd(&stats[col], cs);
                atomicAdd(&stats[N + col], cq);
            }
        }
    }
}

// ---------------------------------------------------------------------------
// CSR build (dst-sorted). P[v] = end offset after fill.
// ---------------------------------------------------------------------------
__global__ __launch_bounds__(256) void csr_count(const int* __restrict__ dst, int* __restrict__ P)
{
    int e = blockIdx.x * 256 + threadIdx.x;
    if (e < N_EDGES) atomicAdd(&P[dst[e] + 1], 1);
}

__global__ __launch_bounds__(1024) void csr_scan(int* __restrict__ P)
{
    __shared__ int part[1024];
    const int t = threadIdx.x;
    const int CH = 49;
    int i0 = t * CH;
    int s = 0;
    for (int i = i0; i < i0 + CH; ++i) {
        if (i <= N_NODES) { s += P[i]; P[i] = s; }
    }
    part[t] = s;
    __syncthreads();
    if (t == 0) {
        int run = 0;
        for (int k = 0; k < 1024; ++k) { int tmp = part[k]; part[k] = run; run += tmp; }
    }
    __syncthreads();
    int off = part[t];
    for (int i = i0; i < i0 + CH; ++i) {
        if (i <= N_NODES) P[i] += off;
    }
}

__global__ __launch_bounds__(256) void csr_fill(
    const int* __restrict__ dst, int* __restrict__ P, int* __restrict__ eids)
{
    int e = blockIdx.x * 256 + threadIdx.x;
    if (e < N_EDGES) {
        int pos = atomicAdd(&P[dst[e]], 1);
        eids[pos] = e;
    }
}

// ---------------------------------------------------------------------------
// Re-sort src + edge_feat(->bf16) into CSR edge order. Runs once.
// ---------------------------------------------------------------------------
__global__ __launch_bounds__(256) void edge_pack_bf(
    const int* __restrict__ src, const int* __restrict__ eids,
    const float* __restrict__ edge_feat, int* __restrict__ es,
    unsigned short* __restrict__ efsb)
{
    int j = blockIdx.x * 256 + threadIdx.x;
    if (j >= N_EDGES) return;
    int e = eids[j];
    es[j] = src[e];
    const float* sp = edge_feat + (size_t)e * EFEAT;
    us8 o0, o1;
#pragma unroll
    for (int k = 0; k < 8; ++k) {
        o0[k] = f2bf(sp[k]);
        o1[k] = f2bf(sp[8 + k]);
    }
    *(us8*)&efsb[(size_t)j * EFEAT] = o0;
    *(us8*)&efsb[(size_t)j * EFEAT + 8] = o1;
}

// ---------------------------------------------------------------------------
// Gather aggregation v8 (MFMA): wave per node, 16-edge groups.
// he = ef @ eW moves to the matrix pipe: per group, one A-frag (16 edges x
// K32: ef[0..15], bias-feature 1.0 at k=16, zeros above) and per dim-chunk
// two B-frags (eW hi/lo in fragment order from LDS) -> 2 chained MFMAs.
// VALU keeps only the hv gather + relu + accumulate. Invalid edge slots
// point their hv load at a -1e30 dummy row so relu zeroes them for free.
// acc stays in C-fragment layout across groups; one shfl_xor(16/32)
// reduction per node, then out = acc_sum + hn[v] -> bf16 [N][320].
// ---------------------------------------------------------------------------
__global__ __launch_bounds__(256, 3) void gather_mf(
    const float* __restrict__ hn, const unsigned short* __restrict__ efsb,
    const int* __restrict__ es, const int* __restrict__ P,
    const unsigned short* __restrict__ eWf, const float* __restrict__ dummy,
    unsigned short* __restrict__ aggH)
{
    __shared__ unsigned short ldsw[19456];   // 38912 B: 19 chunks x 2 planes x 64 lanes x 16B
    const int tid = threadIdx.x;
    const int lane = tid & 63;
    const int w = tid >> 6;

#pragma unroll
    for (int it = 0; it < 10; ++it) {
        int i = tid + it * 256;
        if (i < 2432) load_lds16(eWf + (size_t)i * 8, &ldsw[i * 8]);
    }
    __syncthreads();

    const int n15 = lane & 15;
    const int g = lane >> 4;
    const int r0 = g * 4;
    const int wid = blockIdx.x * 4 + w;

    for (int t = 0; t < 16; ++t) {
        const int v = wid * 16 + t;
        if (v >= N_NODES) return;
        const int j0 = (v == 0) ? 0 : P[v - 1];
        const int j1 = P[v];

        facc4 zero4 = {0.f, 0.f, 0.f, 0.f};
        facc4 acc[19];
#pragma unroll
        for (int c = 0; c < 19; ++c) acc[c] = zero4;

        for (int jb = j0; jb < j1; jb += 16) {
            // A fragment: row = edge slot (lane&15), k-octet g. g=0/1: real
            // ef; g=2: bias feature 1.0 at k=16; g=3: zeros. Rows beyond j1
            // hold neighbor garbage — masked below via the dummy hv row.
            bfrag8 af = {0, 0, 0, 0, 0, 0, 0, 0};
            if (g < 2) {
                int eA = min(jb + n15, N_EDGES - 1);
                af = *(const bfrag8*)&efsb[(size_t)eA * EFEAT + 8 * g];
            } else if (g == 2) {
                af[0] = (short)0x3F80;   // bf16 1.0
            }
            // per-lane row pointers for the 4 C-rows (edge slots r0..r0+3)
            const float* ptr[4];
#pragma unroll
            for (int r = 0; r < 4; ++r) {
                int e = jb + r0 + r;
                int s = es[min(e, N_EDGES - 1)];
                ptr[r] = (e < j1) ? (hn + (size_t)s * DIM + n15) : (dummy + n15);
            }
#pragma unroll
            for (int c = 0; c < 19; ++c) {
                bfrag8 bh = *(const bfrag8*)&ldsw[(c * 128 + lane) * 8];
                bfrag8 bl = *(const bfrag8*)&ldsw[(c * 128 + 64 + lane) * 8];
                facc4 tt = MFMA16(af, bl, zero4);
                tt = MFMA16(af, bh, tt);
#pragma unroll
                for (int r = 0; r < 4; ++r) {
                    float hv = ptr[r][c * 16];
                    acc[c][r] += fmaxf(tt[r] + hv, 0.f);
                }
            }
        }

        // reduce over the 16 edge slots: 4 in-lane rows + 4 lane groups
        float s[19];
#pragma unroll
        for (int c = 0; c < 19; ++c) {
            float x = acc[c][0] + acc[c][1] + acc[c][2] + acc[c][3];
            x += __shfl_xor(x, 16, 64);
            x += __shfl_xor(x, 32, 64);
            s[c] = x;
        }
        // write [v][0..319]: dim d = lane + 64m -> chunk 4m+g, col n15.
#pragma unroll
        for (int m = 0; m < 5; ++m) {
            int d = lane + 64 * m;
            float val = (g == 0) ? s[(4 * m     < 19) ? 4 * m     : 18]
                      : (g == 1) ? s[(4 * m + 1 < 19) ? 4 * m + 1 : 18]
                      : (g == 2) ? s[(4 * m + 2 < 19) ? 4 * m + 2 : 18]
                                 : s[(4 * m + 3 < 19) ? 4 * m + 3 : 18];
            float o = (d < DIM) ? (val + hn[(size_t)v * DIM + d]) : 0.f;
            aggH[(size_t)v * 320 + d] = f2bf(o);
        }
    }
}

// ---------------------------------------------------------------------------
// BN finalize + apply
// ---------------------------------------------------------------------------
__global__ __launch_bounds__(256) void bn_finalize(
    const float* __restrict__ stats, const float* __restrict__ g,
    const float* __restrict__ beta, float* __restrict__ ab, int C)
{
    int c = blockIdx.x * 256 + threadIdx.x;
    if (c >= C) return;
    const float invN = 1.f / (float)N_NODES;
    float m = stats[c] * invN;
    float v = stats[C + c] * invN - m * m;
    float a = g[c] * rsqrtf(v + BN_EPS);
    ab[c] = a;
    ab[C + c] = beta[c] - m * a;
}

__global__ __launch_bounds__(256) void bn_apply(
    const float* __restrict__ x, const float* __restrict__ ab,
    float* __restrict__ y, int total4, int C, int relu)
{
    int i = blockIdx.x * 256 + threadIdx.x;
    if (i >= total4) return;
    float4 v = ((const float4*)x)[i];
    int c = (i << 2) % C;
    const float* a = ab + c;
    const float* bb = ab + C + c;
    float4 r;
    r.x = fmaf(v.x, a[0], bb[0]);
    r.y = fmaf(v.y, a[1], bb[1]);
    r.z = fmaf(v.z, a[2], bb[2]);
    r.w = fmaf(v.w, a[3], bb[3]);
    if (relu) {
        r.x = fmaxf(r.x, 0.f); r.y = fmaxf(r.y, 0.f);
        r.z = fmaxf(r.z, 0.f); r.w = fmaxf(r.w, 0.f);
    }
    ((float4*)y)[i] = r;
}

// ---------------------------------------------------------------------------
// Mean pooling fused with last BN affine: hg = a*mean(h2)+b.
// ---------------------------------------------------------------------------
__global__ __launch_bounds__(256) void pool_seg_bn(
    const float* __restrict__ h2, const int* __restrict__ gid,
    const float* __restrict__ ab, float* __restrict__ hg)
{
    const int g = blockIdx.x;
    int lo = 0, hi = N_NODES;
    while (lo < hi) { int mid = (lo + hi) >> 1; if (gid[mid] < g) lo = mid + 1; else hi = mid; }
    int lo2 = lo, hi2 = N_NODES;
    while (lo2 < hi2) { int mid = (lo2 + hi2) >> 1; if (gid[mid] < g + 1) lo2 = mid + 1; else hi2 = mid; }
    const float inv = 1.f / fmaxf((float)(lo2 - lo), 1.f);
    for (int d = threadIdx.x; d < DIM; d += 256) {
        float s = 0.f;
        for (int r = lo; r < lo2; ++r) s += h2[(size_t)r * DIM + d];
        hg[(size_t)g * DIM + d] = fmaf(s * inv, ab[d], ab[DIM + d]);
    }
}

// fp32 tiled sgemm for the tiny prediction head
#define TS 64
#define BK 16
#define ASP 68

__global__ __launch_bounds__(256) void sgemm_bias(
    const float* __restrict__ A, const float* __restrict__ B,
    const float* __restrict__ bias, float* __restrict__ C,
    int M, int Ncol, int K)
{
    __shared__ float As[BK][ASP];
    __shared__ float Bs[BK][TS];
    const int tid = threadIdx.x;
    const int bm = blockIdx.x * TS;
    const int bn = blockIdx.y * TS;
    const int tm = (tid >> 4) * 4;
    const int tn = (tid & 15) * 4;
    float acc[4][4] = {};

    for (int k0 = 0; k0 < K; k0 += BK) {
#pragma unroll
        for (int i = 0; i < 4; ++i) {
            int idx = tid + i * 256;
            int m = idx >> 4;
            int k = idx & 15;
            int row = bm + m, kk = k0 + k;
            float v = 0.f;
            if (row < M && kk < K) v = A[(size_t)row * K + kk];
            As[k][m] = v;
        }
#pragma unroll
        for (int i = 0; i < 4; ++i) {
            int idx = tid + i * 256;
            int k = idx >> 6;
            int n = idx & 63;
            int col = bn + n, kk = k0 + k;
            float v = 0.f;
            if (col < Ncol && kk < K) v = B[(size_t)kk * Ncol + col];
            Bs[k][n] = v;
        }
        __syncthreads();
#pragma unroll
        for (int k = 0; k < BK; ++k) {
            float4 av = *(const float4*)&As[k][tm];
            float4 bv = *(const float4*)&Bs[k][tn];
            float a4[4] = {av.x, av.y, av.z, av.w};
            float b4[4] = {bv.x, bv.y, bv.z, bv.w};
#pragma unroll
            for (int i = 0; i < 4; ++i)
#pragma unroll
                for (int j = 0; j < 4; ++j)
                    acc[i][j] = fmaf(a4[i], b4[j], acc[i][j]);
        }
        __syncthreads();
    }

#pragma unroll
    for (int i = 0; i < 4; ++i) {
        int row = bm + tm + i;
        if (row >= M) continue;
#pragma unroll
        for (int j = 0; j < 4; ++j) {
            int col = bn + tn + j;
            if (col < Ncol)
                C[(size_t)row * Ncol + col] = acc[i][j] + bias[col];
        }
    }
}

// ---------------------------------------------------------------------------
extern "C" void kernel_launch(void* const* d_in, const int* in_sizes, int n_in,
                              void* d_out, int out_size, void* d_ws, size_t ws_size,
                              hipStream_t stream)
{
    const float* node_feat = (const float*)d_in[0];
    const float* edge_feat = (const float*)d_in[1];
    const int*   src       = (const int*)d_in[2];
    const int*   dst       = (const int*)d_in[3];
    const int*   gid       = (const int*)d_in[4];
    const float* node_W = (const float*)d_in[6];
    const float* node_b = (const float*)d_in[7];
    const float* edge_W = (const float*)d_in[8];
    const float* edge_b = (const float*)d_in[9];
    const float* W1  = (const float*)d_in[10];
    const float* b1  = (const float*)d_in[11];
    const float* g1  = (const float*)d_in[12];
    const float* be1 = (const float*)d_in[13];
    const float* W2  = (const float*)d_in[14];
    const float* b2  = (const float*)d_in[15];
    const float* g2  = (const float*)d_in[16];
    const float* be2 = (const float*)d_in[17];
    const float* pred_W = (const float*)d_in[18];
    const float* pred_b = (const float*)d_in[19];
    float* out = (float*)d_out;

    // ---- workspace layout (bytes), total < 248.73 MB (r9-proven) ----
    char* base = (char*)d_ws;
    float* hn            = (float*)(base + 0);                 // 60,000,000
    float* h2            = hn;                                 // in-place (hn dead after gather)
    float* x1            = (float*)(base + 60000000);          // 120,000,000
    unsigned short* nfH  = (unsigned short*)x1;                // alias (encoder only)
    unsigned short* aggH = (unsigned short*)(base + 180000000);// 32,000,000
    int*   es            = (int*)(base + 212000000);           // 3,200,000
    unsigned short* efsb = (unsigned short*)(base + 215200000);// 25,600,000 (ends 240,800,000)
    float* dummy         = (float*)(base + 243900000);         // 1,280 (-1e30 row; in efsb->wtH gap)
    unsigned short* wtH  = (unsigned short*)(base + 244000000);// <=466,944 (W2: 384x608x2)
    unsigned short* wtL  = (unsigned short*)(base + 244500000);// <=466,944 (ends 244,966,944)
    int*   eids          = (int*)(base + 245000000);           // 3,200,000
    unsigned short* eWf  = (unsigned short*)(base + 245000000);// 38,912 (aliases eids, used after)
    int*   P             = (int*)(base + 248200000);           // 200,004
    float* stats         = (float*)(base + 248400016);
    float* ab            = (float*)(base + 248407216);
    float* hg            = (float*)(base + 248414416);         // 307,200
    float* stats2        = stats + 1200;
    float* ab2           = ab + 1200;

    dim3 blk(256);

    // ---- node encoder: hn = node_feat @ node_W + node_b ----
    tobf4<<<dim3((N_NODES * NFEAT / 4 + 255) / 256), blk, 0, stream>>>(
        node_feat, nfH, N_NODES * NFEAT / 4);
    conv_wt<<<dim3((384 * 128 + 255) / 256), blk, 0, stream>>>(
        node_W, wtH, wtL, NFEAT, DIM, 128, 384);
    gemm_pp<<<dim3(3, 391), blk, 0, stream>>>(
        nfH, wtH, wtL, node_b, hn, N_NODES, DIM, 128, nullptr);

    // ---- CSR by dst + packed edge streams (layer-invariant, run once) ----
    hipMemsetAsync(P, 0, (N_NODES + 1) * sizeof(int), stream);
    csr_count<<<dim3((N_EDGES + 255) / 256), blk, 0, stream>>>(dst, P);
    csr_scan<<<dim3(1), dim3(1024), 0, stream>>>(P);
    csr_fill<<<dim3((N_EDGES + 255) / 256), blk, 0, stream>>>(dst, P, eids);
    edge_pack_bf<<<dim3((N_EDGES + 255) / 256), blk, 0, stream>>>(
        src, eids, edge_feat, es, efsb);
    fill_dummy<<<dim3(2), blk, 0, stream>>>(dummy);

    for (int l = 0; l < N_LAYERS; ++l) {
        // aggH = bf16(hn + sum relu(hn[src] + he))  [N][320], he via MFMA
        conv_ew<<<dim3(10), blk, 0, stream>>>(
            edge_W + (size_t)l * EFEAT * DIM, edge_b + (size_t)l * DIM, eWf);
        gather_mf<<<dim3(782), blk, 0, stream>>>(
            hn, efsb, es, P, eWf, dummy, aggH);

        hipMemsetAsync(stats, 0, 1800 * sizeof(float), stream);

        // x1 = agg @ W1 + b1   [N, 600]  (+ BN1 stats in epilogue)
        conv_wt<<<dim3((640 * 320 + 255) / 256), blk, 0, stream>>>(
            W1 + (size_t)l * DIM * 2 * DIM, wtH, wtL, DIM, 2 * DIM, 320, 640);
        gemm_pp<<<dim3(5, 391), blk, 0, stream>>>(
            aggH, wtH, wtL, b1 + (size_t)l * 2 * DIM, x1,
            N_NODES, 2 * DIM, 320, stats);
        bn_finalize<<<dim3(3), blk, 0, stream>>>(
            stats, g1 + (size_t)l * 2 * DIM, be1 + (size_t)l * 2 * DIM, ab, 2 * DIM);

        // h2(=hn) = relu(bn1(x1)) @ W2 + b2  (BN1 fused in staging; BN2 stats)
        conv_wt<<<dim3((384 * 608 + 255) / 256), blk, 0, stream>>>(
            W2 + (size_t)l * 2 * DIM * DIM, wtH, wtL, 2 * DIM, DIM, 608, 384);
        gemm_af<<<dim3(3, 391), blk, 0, stream>>>(
            x1, wtH, wtL, b2 + (size_t)l * DIM, h2, N_NODES, DIM, 2 * DIM, 608,
            ab, stats2);
        bn_finalize<<<dim3(2), blk, 0, stream>>>(
            stats2, g2 + (size_t)l * DIM, be2 + (size_t)l * DIM, ab2, DIM);

        // hn = bn2(h2) + relu, in place — except last layer (fused into pool)
        if (l < N_LAYERS - 1)
            bn_apply<<<dim3((N_NODES * DIM / 4 + 255) / 256), blk, 0, stream>>>(
                h2, ab2, hn, N_NODES * DIM / 4, DIM, 1);
    }

    // ---- mean pool with fused last-BN affine + head ----
    pool_seg_bn<<<dim3(N_GRAPHS), blk, 0, stream>>>(h2, gid, ab2, hg);
    sgemm_bias<<<dim3((N_GRAPHS + 63) / 64, (OUTD + 63) / 64), blk, 0, stream>>>(
        hg, pred_W, pred_b, out, N_GRAPHS, OUTD, DIM);
}

// Round 3
// 2518.097 us; speedup vs baseline: 1.7699x; 1.7699x over previous
//
#include <hip/hip_runtime.h>

#define N_NODES 50000
#define N_EDGES 800000
#define N_GRAPHS 256
#define N_LAYERS 3
#define DIM 300
#define NFEAT 128
#define EFEAT 16
#define OUTD 128
#define BN_EPS 1e-5f

typedef __attribute__((ext_vector_type(8))) short bfrag8;   // 8 bf16 = 4 VGPR (MFMA A/B operand)
typedef __attribute__((ext_vector_type(4))) float facc4;    // MFMA C/D
typedef __attribute__((ext_vector_type(4))) unsigned short us4;
typedef __attribute__((ext_vector_type(8))) unsigned short us8;

// ---------------- bf16 helpers (RNE) + hi/lo split ----------------
__device__ __forceinline__ unsigned short f2bf(float f) {
    unsigned u = __float_as_uint(f);
    unsigned r = ((u >> 16) & 1u) + 0x7fffu;
    return (unsigned short)((u + r) >> 16);
}
__device__ __forceinline__ float bf2f(unsigned short h) {
    return __uint_as_float(((unsigned)h) << 16);
}
__device__ __forceinline__ void split2(float v, unsigned short& h, unsigned short& l) {
    h = f2bf(v);
    l = f2bf(v - bf2f(h));
}

// async global->LDS, 16B per lane. LDS dest = uniform base + lane*16 (HW rule).
__device__ __forceinline__ void load_lds16(const void* gsrc, void* ldsdst) {
    __builtin_amdgcn_global_load_lds(
        (const __attribute__((address_space(1))) unsigned int*)gsrc,
        (__attribute__((address_space(3))) unsigned int*)ldsdst,
        16, 0, 0);
}

#define MFMA16(a, b, c) __builtin_amdgcn_mfma_f32_16x16x32_bf16(a, b, c, 0, 0, 0)

// ---------------------------------------------------------------------------
// fp32 -> bf16 (hi only), vectorized
// ---------------------------------------------------------------------------
__global__ __launch_bounds__(256) void tobf4(
    const float* __restrict__ x, unsigned short* __restrict__ H, int n4)
{
    int i = blockIdx.x * 256 + threadIdx.x;
    if (i >= n4) return;
    float4 v = ((const float4*)x)[i];
    us4 h;
    h.x = f2bf(v.x); h.y = f2bf(v.y); h.z = f2bf(v.z); h.w = f2bf(v.w);
    ((us4*)H)[i] = h;
}

// ---------------------------------------------------------------------------
// weight conversion: W fp32 [K][N] -> transposed padded hi/lo planes [Np][Kp]
// ---------------------------------------------------------------------------
__global__ __launch_bounds__(256) void conv_wt(
    const float* __restrict__ W, unsigned short* __restrict__ H,
    unsigned short* __restrict__ L, int K, int N, int Kp, int Np)
{
    int idx = blockIdx.x * 256 + threadIdx.x;
    if (idx >= Np * Kp) return;
    int n = idx / Kp;
    int k = idx - n * Kp;
    float v = (n < N && k < K) ? W[(size_t)k * N + n] : 0.f;
    unsigned short h, l;
    split2(v, h, l);
    H[idx] = h;
    L[idx] = l;
}

// ---------------------------------------------------------------------------
// Edge-weight conversion into MFMA B-fragment order for the gather kernel.
// Layout: entry t = c*128 + p*64 + lane (c=dim-chunk 0..18, p=hi/lo plane,
// lane=MFMA lane). Lane holds col n = lane&15 (dim within chunk), k-octet
// g = lane>>4 (k = 8g+i). What k: k<16 -> eW[k][dim]; k==16 -> eb[dim] (bias
// folded as a 17th "constant-1" edge feature); k>16 -> 0.
// ---------------------------------------------------------------------------
__global__ __launch_bounds__(256) void conv_ew(
    const float* __restrict__ eW, const float* __restrict__ eb,
    unsigned short* __restrict__ out)
{
    int t = blockIdx.x * 256 + threadIdx.x;
    if (t >= 2432) return;            // 19 chunks * 2 planes * 64 lanes
    int c = t >> 7;
    int p = (t >> 6) & 1;
    int lane = t & 63;
    int n = lane & 15, g = lane >> 4;
    int col = c * 16 + n;
    us8 o;
#pragma unroll
    for (int i = 0; i < 8; ++i) {
        int k = 8 * g + i;
        float v = 0.f;
        if (col < DIM) {
            if (k < EFEAT) v = eW[k * DIM + col];
            else if (k == EFEAT) v = eb[col];
        }
        unsigned short h, l;
        split2(v, h, l);
        o[i] = p ? l : h;
    }
    *(us8*)&out[(size_t)t * 8] = o;
}

__global__ __launch_bounds__(256) void fill_dummy(float* __restrict__ d)
{
    int i = blockIdx.x * 256 + threadIdx.x;
    if (i < 320) d[i] = -1e30f;
}

// ---------------------------------------------------------------------------
// bf16 MFMA GEMM: A plain bf16 [M][Kp]; B transposed hi/lo planes [Np][Kp].
// acc = Ah*Bh + Ah*Bl (2 MFMA/tile). Block 128x128, BK=32, 4 waves 2x2.
// GRID: blockIdx.x = N-block (fast-varying) so consecutive blocks share the
// same A row-tile -> A L2 reuse across column blocks. blockIdx.y = M-block.
// LDS 24KB: A | Bh | Bl. Optional column-stat epilogue (BN).
// ---------------------------------------------------------------------------
__global__ __launch_bounds__(256, 2) void gemm_pp(
    const unsigned short* __restrict__ Ah,
    const unsigned short* __restrict__ Bth, const unsigned short* __restrict__ Btl,
    const float* __restrict__ bias, float* __restrict__ C,
    int M, int N, int Kp, float* __restrict__ stats)
{
    __shared__ unsigned short lds[12288];   // 24 KB
    const int tid = threadIdx.x;
    const int lane = tid & 63;
    const int w = tid >> 6;
    const int m0 = blockIdx.y * 128;
    const int n0 = blockIdx.x * 128;
    const int wm = (w & 1) * 64;
    const int wn = (w >> 1) * 64;

    const int srow = lane >> 2;
    const int scol = (lane & 3) * 8;

    const unsigned short* gp[6];
    unsigned loff[6];
#pragma unroll
    for (int i = 0; i < 6; ++i) {
        int c = w * 6 + i;
        const unsigned short* pl = (c < 8) ? Ah : (c < 16) ? Bth : Btl;
        int rowg;
        if (c < 8) {
            rowg = m0 + (c & 7) * 16 + srow;
            rowg = min(rowg, M - 1);
        } else {
            rowg = n0 + (c & 7) * 16 + srow;
        }
        gp[i] = pl + (size_t)rowg * Kp + scol;
        loff[i] = c * 512;
    }

    facc4 acc[4][4];
    facc4 zero = {0.f, 0.f, 0.f, 0.f};
#pragma unroll
    for (int i = 0; i < 4; ++i)
#pragma unroll
        for (int j = 0; j < 4; ++j) acc[i][j] = zero;

    const int fr = lane & 15;
    const int fq = (lane >> 4) * 8;

    for (int k0 = 0; k0 < Kp; k0 += 32) {
#pragma unroll
        for (int i = 0; i < 6; ++i) {
            load_lds16(gp[i], &lds[loff[i]]);
            gp[i] += 32;
        }
        __syncthreads();

        bfrag8 ah[4], bh[4], bl[4];
#pragma unroll
        for (int t = 0; t < 4; ++t) {
            int ar = wm + t * 16 + fr;
            ah[t] = *(const bfrag8*)&lds[ar * 32 + fq];
            int br = wn + t * 16 + fr;
            bh[t] = *(const bfrag8*)&lds[4096 + br * 32 + fq];
            bl[t] = *(const bfrag8*)&lds[8192 + br * 32 + fq];
        }
#pragma unroll
        for (int i = 0; i < 4; ++i)
#pragma unroll
            for (int j = 0; j < 4; ++j) {
                acc[i][j] = MFMA16(ah[i], bh[j], acc[i][j]);
                acc[i][j] = MFMA16(ah[i], bl[j], acc[i][j]);
            }
        __syncthreads();
    }

    // epilogue: C/D layout col=lane&15, row=(lane>>4)*4+reg
#pragma unroll
    for (int i = 0; i < 4; ++i)
#pragma unroll
        for (int j = 0; j < 4; ++j) {
            int col = n0 + wn + j * 16 + (lane & 15);
            if (col >= N) continue;
            float bv = bias[col];
#pragma unroll
            for (int r = 0; r < 4; ++r) {
                int row = m0 + wm + i * 16 + (lane >> 4) * 4 + r;
                if (row < M)
                    C[(size_t)row * N + col] = acc[i][j][r] + bv;
            }
        }

    if (stats != nullptr) {
#pragma unroll
        for (int j = 0; j < 4; ++j) {
            int col = n0 + wn + j * 16 + (lane & 15);
            float cs = 0.f, cq = 0.f;
            if (col < N) {
                float bv = bias[col];
#pragma unroll
                for (int i = 0; i < 4; ++i)
#pragma unroll
                    for (int r = 0; r < 4; ++r) {
                        int row = m0 + wm + i * 16 + (lane >> 4) * 4 + r;
                        if (row < M) {
                            float y = acc[i][j][r] + bv;
                            cs += y;
                            cq = fmaf(y, y, cq);
                        }
                    }
            }
            cs += __shfl_xor(cs, 16, 64); cq += __shfl_xor(cq, 16, 64);
            cs += __shfl_xor(cs, 32, 64); cq += __shfl_xor(cq, 32, 64);
            if ((lane >> 4) == 0 && col < N) {
                atomicAdd(&stats[col], cs);
                atomicAdd(&stats[N + col], cq);
            }
        }
    }
}

// ---------------------------------------------------------------------------
// bf16 MFMA GEMM, A fp32 with fused BN-affine+ReLU applied during staging
// (abn = [a K | b K], y = relu(x*a+b)) -> bf16 hi only. Grid transposed as
// gemm_pp (x=N-block) for A L2 reuse. Column-stat epilogue for BN2.
// ---------------------------------------------------------------------------
__global__ __launch_bounds__(256, 2) void gemm_af(
    const float* __restrict__ A, const unsigned short* __restrict__ Bth,
    const unsigned short* __restrict__ Btl, const float* __restrict__ bias,
    float* __restrict__ C, int M, int N, int K, int Kp,
    const float* __restrict__ abn, float* __restrict__ stats)
{
    __shared__ unsigned short lds[12288];
    const int tid = threadIdx.x;
    const int lane = tid & 63;
    const int w = tid >> 6;
    const int m0 = blockIdx.y * 128;
    const int n0 = blockIdx.x * 128;
    const int wm = (w & 1) * 64;
    const int wn = (w >> 1) * 64;

    const int srow = lane >> 2;
    const int scol = (lane & 3) * 8;

    const unsigned short* gpb[4];
    unsigned loffb[4];
#pragma unroll
    for (int i = 0; i < 4; ++i) {
        int c = w * 4 + i;
        const unsigned short* pl = (c < 8) ? Bth : Btl;
        int rowg = n0 + (c & 7) * 16 + srow;
        gpb[i] = pl + (size_t)rowg * Kp + scol;
        loffb[i] = 4096 + c * 512;
    }

    facc4 acc[4][4];
    facc4 zero = {0.f, 0.f, 0.f, 0.f};
#pragma unroll
    for (int i = 0; i < 4; ++i)
#pragma unroll
        for (int j = 0; j < 4; ++j) acc[i][j] = zero;

    const int fr = lane & 15;
    const int fq = (lane >> 4) * 8;

    for (int k0 = 0; k0 < Kp; k0 += 32) {
#pragma unroll
        for (int i = 0; i < 4; ++i) {
            load_lds16(gpb[i], &lds[loffb[i]]);
            gpb[i] += 32;
        }
        // A fp32 -> BN affine + relu -> bf16 into LDS (128 rows x 32 k)
#pragma unroll
        for (int i = 0; i < 4; ++i) {
            int idx = tid + i * 256;
            int row = idx >> 3;
            int q4 = idx & 7;
            int rg = min(m0 + row, M - 1);
            int kk = k0 + q4 * 4;
            us4 h;
            if (kk < K) {
                float4 v = *(const float4*)&A[(size_t)rg * K + kk];
                float4 sa = *(const float4*)&abn[kk];
                float4 sb = *(const float4*)&abn[K + kk];
                h.x = f2bf(fmaxf(fmaf(v.x, sa.x, sb.x), 0.f));
                h.y = f2bf(fmaxf(fmaf(v.y, sa.y, sb.y), 0.f));
                h.z = f2bf(fmaxf(fmaf(v.z, sa.z, sb.z), 0.f));
                h.w = f2bf(fmaxf(fmaf(v.w, sa.w, sb.w), 0.f));
            } else {
                h.x = 0; h.y = 0; h.z = 0; h.w = 0;
            }
            *(us4*)&lds[row * 32 + q4 * 4] = h;
        }
        __syncthreads();

        bfrag8 ah[4], bh[4], bl[4];
#pragma unroll
        for (int t = 0; t < 4; ++t) {
            int ar = wm + t * 16 + fr;
            ah[t] = *(const bfrag8*)&lds[ar * 32 + fq];
            int br = wn + t * 16 + fr;
            bh[t] = *(const bfrag8*)&lds[4096 + br * 32 + fq];
            bl[t] = *(const bfrag8*)&lds[8192 + br * 32 + fq];
        }
#pragma unroll
        for (int i = 0; i < 4; ++i)
#pragma unroll
            for (int j = 0; j < 4; ++j) {
                acc[i][j] = MFMA16(ah[i], bh[j], acc[i][j]);
                acc[i][j] = MFMA16(ah[i], bl[j], acc[i][j]);
            }
        __syncthreads();
    }

#pragma unroll
    for (int i = 0; i < 4; ++i)
#pragma unroll
        for (int j = 0; j < 4; ++j) {
            int col = n0 + wn + j * 16 + (lane & 15);
            if (col >= N) continue;
            float bv = bias[col];
#pragma unroll
            for (int r = 0; r < 4; ++r) {
                int row = m0 + wm + i * 16 + (lane >> 4) * 4 + r;
                if (row < M)
                    C[(size_t)row * N + col] = acc[i][j][r] + bv;
            }
        }

    if (stats != nullptr) {
#pragma unroll
        for (int j = 0; j < 4; ++j) {
            int col = n0 + wn + j * 16 + (lane & 15);
            float cs = 0.f, cq = 0.f;
            if (col < N) {
                float bv = bias[col];
#pragma unroll
                for (int i = 0; i < 4; ++i)
#pragma unroll
                    for (int r = 0; r < 4; ++r) {
                        int row = m0 + wm + i * 16 + (lane >> 4) * 4 + r;
                        if (row < M) {
                            float y = acc[i][j][r] + bv;
                            cs += y;
                            cq = fmaf(y, y, cq);
                        }
                    }
            }
            cs += __shfl_xor(cs, 16, 64); cq += __shfl_xor(cq, 16, 64);
            cs += __shfl_xor(cs, 32, 64); cq += __shfl_xor(cq, 32, 64);
            if ((lane >> 4) == 0 && col < N) {
                atomicAdd(&stats[col], cs);
                atomicAdd(&stats[N + col], cq);
            }
        }
    }
}

// ---------------------------------------------------------------------------
// CSR build (dst-sorted). P[v] = end offset after fill.
// ---------------------------------------------------------------------------
__global__ __launch_bounds__(256) void csr_count(const int* __restrict__ dst, int* __restrict__ P)
{
    int e = blockIdx.x * 256 + threadIdx.x;
    if (e < N_EDGES) atomicAdd(&P[dst[e] + 1], 1);
}

__global__ __launch_bounds__(1024) void csr_scan(int* __restrict__ P)
{
    __shared__ int part[1024];
    const int t = threadIdx.x;
    const int CH = 49;
    int i0 = t * CH;
    int s = 0;
    for (int i = i0; i < i0 + CH; ++i) {
        if (i <= N_NODES) { s += P[i]; P[i] = s; }
    }
    part[t] = s;
    __syncthreads();
    if (t == 0) {
        int run = 0;
        for (int k = 0; k < 1024; ++k) { int tmp = part[k]; part[k] = run; run += tmp; }
    }
    __syncthreads();
    int off = part[t];
    for (int i = i0; i < i0 + CH; ++i) {
        if (i <= N_NODES) P[i] += off;
    }
}

__global__ __launch_bounds__(256) void csr_fill(
    const int* __restrict__ dst, int* __restrict__ P, int* __restrict__ eids)
{
    int e = blockIdx.x * 256 + threadIdx.x;
    if (e < N_EDGES) {
        int pos = atomicAdd(&P[dst[e]], 1);
        eids[pos] = e;
    }
}

// ---------------------------------------------------------------------------
// Re-sort src + edge_feat(->bf16) into CSR edge order. Runs once.
// ---------------------------------------------------------------------------
__global__ __launch_bounds__(256) void edge_pack_bf(
    const int* __restrict__ src, const int* __restrict__ eids,
    const float* __restrict__ edge_feat, int* __restrict__ es,
    unsigned short* __restrict__ efsb)
{
    int j = blockIdx.x * 256 + threadIdx.x;
    if (j >= N_EDGES) return;
    int e = eids[j];
    es[j] = src[e];
    const float* sp = edge_feat + (size_t)e * EFEAT;
    us8 o0, o1;
#pragma unroll
    for (int k = 0; k < 8; ++k) {
        o0[k] = f2bf(sp[k]);
        o1[k] = f2bf(sp[8 + k]);
    }
    *(us8*)&efsb[(size_t)j * EFEAT] = o0;
    *(us8*)&efsb[(size_t)j * EFEAT + 8] = o1;
}

// ---------------------------------------------------------------------------
// Gather aggregation v9 (MFMA, spill-free): BLOCK per node, wave w owns dim
// chunks [5w, min(5w+5,19)). Per 16-edge group: one A-frag per wave (16 edges
// x K32: ef, bias-feature at k=16), per owned chunk two B-frags (eW hi/lo
// from LDS) -> 2 chained MFMAs. Persistent state acc[5][4] = 20 VGPR (v8's
// acc[19][4]=76 spilled to scratch: 1.2GB WRITE_SIZE, 1055us). Invalid edge
// slots read a -1e30 dummy row so relu kills them. No inter-wave sync after
// weight staging: chunks are independent. Block walks NPB=16 nodes.
// ---------------------------------------------------------------------------
#define NPB 16

__global__ __launch_bounds__(256, 4) void gather_mf(
    const float* __restrict__ hn, const unsigned short* __restrict__ efsb,
    const int* __restrict__ es, const int* __restrict__ P,
    const unsigned short* __restrict__ eWf, const float* __restrict__ dummy,
    unsigned short* __restrict__ aggH)
{
    __shared__ unsigned short ldsw[19456];   // 38912 B: 19 chunks x 2 planes x 64 lanes x 16B
    const int tid = threadIdx.x;
    const int lane = tid & 63;
    const int w = tid >> 6;

#pragma unroll
    for (int it = 0; it < 10; ++it) {
        int i = tid + it * 256;
        if (i < 2432) load_lds16(eWf + (size_t)i * 8, &ldsw[i * 8]);
    }
    __syncthreads();

    const int n15 = lane & 15;
    const int g = lane >> 4;
    const int r0 = g * 4;
    const int c0 = w * 5;                 // chunks [c0, min(c0+5,19))

    for (int t = 0; t < NPB; ++t) {
        const int v = blockIdx.x * NPB + t;
        if (v >= N_NODES) return;
        const int j0 = (v == 0) ? 0 : P[v - 1];
        const int j1 = P[v];

        facc4 zero4 = {0.f, 0.f, 0.f, 0.f};
        facc4 acc[5];
#pragma unroll
        for (int i = 0; i < 5; ++i) acc[i] = zero4;

        for (int jb = j0; jb < j1; jb += 16) {
            // A fragment: row = edge slot (lane&15), k-octet g. g=0/1: real
            // ef; g=2: bias feature 1.0 at k=16; g=3: zeros. Rows beyond j1
            // hold neighbor garbage — masked below via the dummy hv row.
            bfrag8 af = {0, 0, 0, 0, 0, 0, 0, 0};
            if (g < 2) {
                int eA = min(jb + n15, N_EDGES - 1);
                af = *(const bfrag8*)&efsb[(size_t)eA * EFEAT + 8 * g];
            } else if (g == 2) {
                af[0] = (short)0x3F80;   // bf16 1.0
            }
            // per-lane row pointers for the 4 C-rows (edge slots r0..r0+3)
            const float* ptr[4];
#pragma unroll
            for (int r = 0; r < 4; ++r) {
                int e = jb + r0 + r;
                int s = es[min(e, N_EDGES - 1)];
                ptr[r] = (e < j1) ? (hn + (size_t)s * DIM + n15) : (dummy + n15);
            }
#pragma unroll
            for (int i = 0; i < 5; ++i) {
                int c = c0 + i;
                if (c < 19) {             // wave-uniform (w==3 skips i==4)
                    bfrag8 bh = *(const bfrag8*)&ldsw[(c * 128 + lane) * 8];
                    bfrag8 bl = *(const bfrag8*)&ldsw[(c * 128 + 64 + lane) * 8];
                    facc4 tt = MFMA16(af, bl, zero4);
                    tt = MFMA16(af, bh, tt);
#pragma unroll
                    for (int r = 0; r < 4; ++r) {
                        float hv = ptr[r][c * 16];
                        acc[i][r] += fmaxf(tt[r] + hv, 0.f);
                    }
                }
            }
        }

        // reduce over the 16 edge slots: 4 in-lane rows + 4 lane groups
        float s[5];
#pragma unroll
        for (int i = 0; i < 5; ++i) {
            float x = acc[i][0] + acc[i][1] + acc[i][2] + acc[i][3];
            x += __shfl_xor(x, 16, 64);
            x += __shfl_xor(x, 32, 64);
            s[i] = x;
        }
        // write: chunk c=c0+i, col d=c*16+n15, one lane-group per chunk
        // (i%4 -> group), + hn[v] residual. Wave 3 / group 1 zero-pads
        // cols 304..319 (never covered by a chunk; gemm reads Kp=320).
#pragma unroll
        for (int i = 0; i < 5; ++i) {
            int c = c0 + i;
            int writer = i & 3;
            if (c < 19 && g == writer) {
                int d = c * 16 + n15;
                float o = 0.f;
                if (d < DIM) o = s[i] + hn[(size_t)v * DIM + d];
                aggH[(size_t)v * 320 + d] = f2bf(o);
            }
        }
        if (w == 3 && g == 1)
            aggH[(size_t)v * 320 + 304 + n15] = 0;
    }
}

// ---------------------------------------------------------------------------
// BN finalize + apply
// ---------------------------------------------------------------------------
__global__ __launch_bounds__(256) void bn_finalize(
    const float* __restrict__ stats, const float* __restrict__ g,
    const float* __restrict__ beta, float* __restrict__ ab, int C)
{
    int c = blockIdx.x * 256 + threadIdx.x;
    if (c >= C) return;
    const float invN = 1.f / (float)N_NODES;
    float m = stats[c] * invN;
    float v = stats[C + c] * invN - m * m;
    float a = g[c] * rsqrtf(v + BN_EPS);
    ab[c] = a;
    ab[C + c] = beta[c] - m * a;
}

__global__ __launch_bounds__(256) void bn_apply(
    const float* __restrict__ x, const float* __restrict__ ab,
    float* __restrict__ y, int total4, int C, int relu)
{
    int i = blockIdx.x * 256 + threadIdx.x;
    if (i >= total4) return;
    float4 v = ((const float4*)x)[i];
    int c = (i << 2) % C;
    const float* a = ab + c;
    const float* bb = ab + C + c;
    float4 r;
    r.x = fmaf(v.x, a[0], bb[0]);
    r.y = fmaf(v.y, a[1], bb[1]);
    r.z = fmaf(v.z, a[2], bb[2]);
    r.w = fmaf(v.w, a[3], bb[3]);
    if (relu) {
        r.x = fmaxf(r.x, 0.f); r.y = fmaxf(r.y, 0.f);
        r.z = fmaxf(r.z, 0.f); r.w = fmaxf(r.w, 0.f);
    }
    ((float4*)y)[i] = r;
}

// ---------------------------------------------------------------------------
// Mean pooling fused with last BN affine: hg = a*mean(h2)+b.
// ---------------------------------------------------------------------------
__global__ __launch_bounds__(256) void pool_seg_bn(
    const float* __restrict__ h2, const int* __restrict__ gid,
    const float* __restrict__ ab, float* __restrict__ hg)
{
    const int g = blockIdx.x;
    int lo = 0, hi = N_NODES;
    while (lo < hi) { int mid = (lo + hi) >> 1; if (gid[mid] < g) lo = mid + 1; else hi = mid; }
    int lo2 = lo, hi2 = N_NODES;
    while (lo2 < hi2) { int mid = (lo2 + hi2) >> 1; if (gid[mid] < g + 1) lo2 = mid + 1; else hi2 = mid; }
    const float inv = 1.f / fmaxf((float)(lo2 - lo), 1.f);
    for (int d = threadIdx.x; d < DIM; d += 256) {
        float s = 0.f;
        for (int r = lo; r < lo2; ++r) s += h2[(size_t)r * DIM + d];
        hg[(size_t)g * DIM + d] = fmaf(s * inv, ab[d], ab[DIM + d]);
    }
}

// fp32 tiled sgemm for the tiny prediction head
#define TS 64
#define BK 16
#define ASP 68

__global__ __launch_bounds__(256) void sgemm_bias(
    const float* __restrict__ A, const float* __restrict__ B,
    const float* __restrict__ bias, float* __restrict__ C,
    int M, int Ncol, int K)
{
    __shared__ float As[BK][ASP];
    __shared__ float Bs[BK][TS];
    const int tid = threadIdx.x;
    const int bm = blockIdx.x * TS;
    const int bn = blockIdx.y * TS;
    const int tm = (tid >> 4) * 4;
    const int tn = (tid & 15) * 4;
    float acc[4][4] = {};

    for (int k0 = 0; k0 < K; k0 += BK) {
#pragma unroll
        for (int i = 0; i < 4; ++i) {
            int idx = tid + i * 256;
            int m = idx >> 4;
            int k = idx & 15;
            int row = bm + m, kk = k0 + k;
            float v = 0.f;
            if (row < M && kk < K) v = A[(size_t)row * K + kk];
            As[k][m] = v;
        }
#pragma unroll
        for (int i = 0; i < 4; ++i) {
            int idx = tid + i * 256;
            int k = idx >> 6;
            int n = idx & 63;
            int col = bn + n, kk = k0 + k;
            float v = 0.f;
            if (col < Ncol && kk < K) v = B[(size_t)kk * Ncol + col];
            Bs[k][n] = v;
        }
        __syncthreads();
#pragma unroll
        for (int k = 0; k < BK; ++k) {
            float4 av = *(const float4*)&As[k][tm];
            float4 bv = *(const float4*)&Bs[k][tn];
            float a4[4] = {av.x, av.y, av.z, av.w};
            float b4[4] = {bv.x, bv.y, bv.z, bv.w};
#pragma unroll
            for (int i = 0; i < 4; ++i)
#pragma unroll
                for (int j = 0; j < 4; ++j)
                    acc[i][j] = fmaf(a4[i], b4[j], acc[i][j]);
        }
        __syncthreads();
    }

#pragma unroll
    for (int i = 0; i < 4; ++i) {
        int row = bm + tm + i;
        if (row >= M) continue;
#pragma unroll
        for (int j = 0; j < 4; ++j) {
            int col = bn + tn + j;
            if (col < Ncol)
                C[(size_t)row * Ncol + col] = acc[i][j] + bias[col];
        }
    }
}

// ---------------------------------------------------------------------------
extern "C" void kernel_launch(void* const* d_in, const int* in_sizes, int n_in,
                              void* d_out, int out_size, void* d_ws, size_t ws_size,
                              hipStream_t stream)
{
    const float* node_feat = (const float*)d_in[0];
    const float* edge_feat = (const float*)d_in[1];
    const int*   src       = (const int*)d_in[2];
    const int*   dst       = (const int*)d_in[3];
    const int*   gid       = (const int*)d_in[4];
    const float* node_W = (const float*)d_in[6];
    const float* node_b = (const float*)d_in[7];
    const float* edge_W = (const float*)d_in[8];
    const float* edge_b = (const float*)d_in[9];
    const float* W1  = (const float*)d_in[10];
    const float* b1  = (const float*)d_in[11];
    const float* g1  = (const float*)d_in[12];
    const float* be1 = (const float*)d_in[13];
    const float* W2  = (const float*)d_in[14];
    const float* b2  = (const float*)d_in[15];
    const float* g2  = (const float*)d_in[16];
    const float* be2 = (const float*)d_in[17];
    const float* pred_W = (const float*)d_in[18];
    const float* pred_b = (const float*)d_in[19];
    float* out = (float*)d_out;

    // ---- workspace layout (bytes), total < 248.73 MB (r9-proven) ----
    char* base = (char*)d_ws;
    float* hn            = (float*)(base + 0);                 // 60,000,000
    float* h2            = hn;                                 // in-place (hn dead after gather)
    float* x1            = (float*)(base + 60000000);          // 120,000,000
    unsigned short* nfH  = (unsigned short*)x1;                // alias (encoder only)
    unsigned short* aggH = (unsigned short*)(base + 180000000);// 32,000,000
    int*   es            = (int*)(base + 212000000);           // 3,200,000
    unsigned short* efsb = (unsigned short*)(base + 215200000);// 25,600,000 (ends 240,800,000)
    float* dummy         = (float*)(base + 243900000);         // 1,280 (-1e30 row; in efsb->wtH gap)
    unsigned short* wtH  = (unsigned short*)(base + 244000000);// <=466,944 (W2: 384x608x2)
    unsigned short* wtL  = (unsigned short*)(base + 244500000);// <=466,944 (ends 244,966,944)
    int*   eids          = (int*)(base + 245000000);           // 3,200,000
    unsigned short* eWf  = (unsigned short*)(base + 245000000);// 38,912 (aliases eids, used after)
    int*   P             = (int*)(base + 248200000);           // 200,004
    float* stats         = (float*)(base + 248400016);
    float* ab            = (float*)(base + 248407216);
    float* hg            = (float*)(base + 248414416);         // 307,200
    float* stats2        = stats + 1200;
    float* ab2           = ab + 1200;

    dim3 blk(256);

    // ---- node encoder: hn = node_feat @ node_W + node_b ----
    tobf4<<<dim3((N_NODES * NFEAT / 4 + 255) / 256), blk, 0, stream>>>(
        node_feat, nfH, N_NODES * NFEAT / 4);
    conv_wt<<<dim3((384 * 128 + 255) / 256), blk, 0, stream>>>(
        node_W, wtH, wtL, NFEAT, DIM, 128, 384);
    gemm_pp<<<dim3(3, 391), blk, 0, stream>>>(
        nfH, wtH, wtL, node_b, hn, N_NODES, DIM, 128, nullptr);

    // ---- CSR by dst + packed edge streams (layer-invariant, run once) ----
    hipMemsetAsync(P, 0, (N_NODES + 1) * sizeof(int), stream);
    csr_count<<<dim3((N_EDGES + 255) / 256), blk, 0, stream>>>(dst, P);
    csr_scan<<<dim3(1), dim3(1024), 0, stream>>>(P);
    csr_fill<<<dim3((N_EDGES + 255) / 256), blk, 0, stream>>>(dst, P, eids);
    edge_pack_bf<<<dim3((N_EDGES + 255) / 256), blk, 0, stream>>>(
        src, eids, edge_feat, es, efsb);
    fill_dummy<<<dim3(2), blk, 0, stream>>>(dummy);

    for (int l = 0; l < N_LAYERS; ++l) {
        // aggH = bf16(hn + sum relu(hn[src] + he))  [N][320], he via MFMA
        conv_ew<<<dim3(10), blk, 0, stream>>>(
            edge_W + (size_t)l * EFEAT * DIM, edge_b + (size_t)l * DIM, eWf);
        gather_mf<<<dim3((N_NODES + NPB - 1) / NPB), blk, 0, stream>>>(
            hn, efsb, es, P, eWf, dummy, aggH);

        hipMemsetAsync(stats, 0, 1800 * sizeof(float), stream);

        // x1 = agg @ W1 + b1   [N, 600]  (+ BN1 stats in epilogue)
        conv_wt<<<dim3((640 * 320 + 255) / 256), blk, 0, stream>>>(
            W1 + (size_t)l * DIM * 2 * DIM, wtH, wtL, DIM, 2 * DIM, 320, 640);
        gemm_pp<<<dim3(5, 391), blk, 0, stream>>>(
            aggH, wtH, wtL, b1 + (size_t)l * 2 * DIM, x1,
            N_NODES, 2 * DIM, 320, stats);
        bn_finalize<<<dim3(3), blk, 0, stream>>>(
            stats, g1 + (size_t)l * 2 * DIM, be1 + (size_t)l * 2 * DIM, ab, 2 * DIM);

        // h2(=hn) = relu(bn1(x1)) @ W2 + b2  (BN1 fused in staging; BN2 stats)
        conv_wt<<<dim3((384 * 608 + 255) / 256), blk, 0, stream>>>(
            W2 + (size_t)l * 2 * DIM * DIM, wtH, wtL, 2 * DIM, DIM, 608, 384);
        gemm_af<<<dim3(3, 391), blk, 0, stream>>>(
            x1, wtH, wtL, b2 + (size_t)l * DIM, h2, N_NODES, DIM, 2 * DIM, 608,
            ab, stats2);
        bn_finalize<<<dim3(2), blk, 0, stream>>>(
            stats2, g2 + (size_t)l * DIM, be2 + (size_t)l * DIM, ab2, DIM);

        // hn = bn2(h2) + relu, in place — except last layer (fused into pool)
        if (l < N_LAYERS - 1)
            bn_apply<<<dim3((N_NODES * DIM / 4 + 255) / 256), blk, 0, stream>>>(
                h2, ab2, hn, N_NODES * DIM / 4, DIM, 1);
    }

    // ---- mean pool with fused last-BN affine + head ----
    pool_seg_bn<<<dim3(N_GRAPHS), blk, 0, stream>>>(h2, gid, ab2, hg);
    sgemm_bias<<<dim3((N_GRAPHS + 63) / 64, (OUTD + 63) / 64), blk, 0, stream>>>(
        hg, pred_W, pred_b, out, N_GRAPHS, OUTD, DIM);
}

// Round 4
// 2347.324 us; speedup vs baseline: 1.8986x; 1.0728x over previous
//
#include <hip/hip_runtime.h>

#define N_NODES 50000
#define N_EDGES 800000
#define N_GRAPHS 256
#define N_LAYERS 3
#define DIM 300
#define NFEAT 128
#define EFEAT 16
#define OUTD 128
#define BN_EPS 1e-5f

typedef __attribute__((ext_vector_type(8))) short bfrag8;   // 8 bf16 = 4 VGPR (MFMA A/B operand)
typedef __attribute__((ext_vector_type(4))) float facc4;    // MFMA C/D
typedef __attribute__((ext_vector_type(4))) unsigned short us4;
typedef __attribute__((ext_vector_type(8))) unsigned short us8;

// ---------------- bf16 helpers (RNE) + hi/lo split ----------------
__device__ __forceinline__ unsigned short f2bf(float f) {
    unsigned u = __float_as_uint(f);
    unsigned r = ((u >> 16) & 1u) + 0x7fffu;
    return (unsigned short)((u + r) >> 16);
}
__device__ __forceinline__ float bf2f(unsigned short h) {
    return __uint_as_float(((unsigned)h) << 16);
}
__device__ __forceinline__ void split2(float v, unsigned short& h, unsigned short& l) {
    h = f2bf(v);
    l = f2bf(v - bf2f(h));
}

// async global->LDS, 16B per lane. LDS dest = uniform base + lane*16 (HW rule).
__device__ __forceinline__ void load_lds16(const void* gsrc, void* ldsdst) {
    __builtin_amdgcn_global_load_lds(
        (const __attribute__((address_space(1))) unsigned int*)gsrc,
        (__attribute__((address_space(3))) unsigned int*)ldsdst,
        16, 0, 0);
}

#define MFMA16(a, b, c) __builtin_amdgcn_mfma_f32_16x16x32_bf16(a, b, c, 0, 0, 0)

// ---------------------------------------------------------------------------
// fp32 -> bf16 (hi only), vectorized
// ---------------------------------------------------------------------------
__global__ __launch_bounds__(256) void tobf4(
    const float* __restrict__ x, unsigned short* __restrict__ H, int n4)
{
    int i = blockIdx.x * 256 + threadIdx.x;
    if (i >= n4) return;
    float4 v = ((const float4*)x)[i];
    us4 h;
    h.x = f2bf(v.x); h.y = f2bf(v.y); h.z = f2bf(v.z); h.w = f2bf(v.w);
    ((us4*)H)[i] = h;
}

// ---------------------------------------------------------------------------
// weight conversion: W fp32 [K][N] -> transposed padded hi/lo planes [Np][Kp]
// ---------------------------------------------------------------------------
__global__ __launch_bounds__(256) void conv_wt(
    const float* __restrict__ W, unsigned short* __restrict__ H,
    unsigned short* __restrict__ L, int K, int N, int Kp, int Np)
{
    int idx = blockIdx.x * 256 + threadIdx.x;
    if (idx >= Np * Kp) return;
    int n = idx / Kp;
    int k = idx - n * Kp;
    float v = (n < N && k < K) ? W[(size_t)k * N + n] : 0.f;
    unsigned short h, l;
    split2(v, h, l);
    H[idx] = h;
    L[idx] = l;
}

// ---------------------------------------------------------------------------
// Edge-weight conversion into MFMA B-fragment order for the gather kernel.
// Layout: entry t = c*128 + p*64 + lane (c=dim-chunk 0..18, p=hi/lo plane,
// lane=MFMA lane). Lane holds col n = lane&15 (dim within chunk), k-octet
// g = lane>>4 (k = 8g+i). What k: k<16 -> eW[k][dim]; k==16 -> eb[dim] (bias
// folded as a 17th "constant-1" edge feature); k>16 -> 0.
// ---------------------------------------------------------------------------
__global__ __launch_bounds__(256) void conv_ew(
    const float* __restrict__ eW, const float* __restrict__ eb,
    unsigned short* __restrict__ out)
{
    int t = blockIdx.x * 256 + threadIdx.x;
    if (t >= 2432) return;            // 19 chunks * 2 planes * 64 lanes
    int c = t >> 7;
    int p = (t >> 6) & 1;
    int lane = t & 63;
    int n = lane & 15, g = lane >> 4;
    int col = c * 16 + n;
    us8 o;
#pragma unroll
    for (int i = 0; i < 8; ++i) {
        int k = 8 * g + i;
        float v = 0.f;
        if (col < DIM) {
            if (k < EFEAT) v = eW[k * DIM + col];
            else if (k == EFEAT) v = eb[col];
        }
        unsigned short h, l;
        split2(v, h, l);
        o[i] = p ? l : h;
    }
    *(us8*)&out[(size_t)t * 8] = o;
}

__global__ __launch_bounds__(256) void fill_dummy(float* __restrict__ d)
{
    int i = blockIdx.x * 256 + threadIdx.x;
    if (i < 320) d[i] = -1e30f;
}

// ---------------------------------------------------------------------------
// bf16 MFMA GEMM: A plain bf16 [M][Kp]; B transposed hi/lo planes [Np][Kp].
// acc = Ah*Bh + Ah*Bl (2 MFMA/tile). Block 128x128, BK=32, 4 waves 2x2.
// GRID: blockIdx.x = N-block (fast-varying) so consecutive blocks share the
// same A row-tile -> A L2 reuse across column blocks. blockIdx.y = M-block.
// LDS 24KB: A | Bh | Bl. Optional column-stat epilogue (BN).
// ---------------------------------------------------------------------------
__global__ __launch_bounds__(256, 2) void gemm_pp(
    const unsigned short* __restrict__ Ah,
    const unsigned short* __restrict__ Bth, const unsigned short* __restrict__ Btl,
    const float* __restrict__ bias, float* __restrict__ C,
    int M, int N, int Kp, float* __restrict__ stats)
{
    __shared__ unsigned short lds[12288];   // 24 KB
    const int tid = threadIdx.x;
    const int lane = tid & 63;
    const int w = tid >> 6;
    const int m0 = blockIdx.y * 128;
    const int n0 = blockIdx.x * 128;
    const int wm = (w & 1) * 64;
    const int wn = (w >> 1) * 64;

    const int srow = lane >> 2;
    const int scol = (lane & 3) * 8;

    const unsigned short* gp[6];
    unsigned loff[6];
#pragma unroll
    for (int i = 0; i < 6; ++i) {
        int c = w * 6 + i;
        const unsigned short* pl = (c < 8) ? Ah : (c < 16) ? Bth : Btl;
        int rowg;
        if (c < 8) {
            rowg = m0 + (c & 7) * 16 + srow;
            rowg = min(rowg, M - 1);
        } else {
            rowg = n0 + (c & 7) * 16 + srow;
        }
        gp[i] = pl + (size_t)rowg * Kp + scol;
        loff[i] = c * 512;
    }

    facc4 acc[4][4];
    facc4 zero = {0.f, 0.f, 0.f, 0.f};
#pragma unroll
    for (int i = 0; i < 4; ++i)
#pragma unroll
        for (int j = 0; j < 4; ++j) acc[i][j] = zero;

    const int fr = lane & 15;
    const int fq = (lane >> 4) * 8;

    for (int k0 = 0; k0 < Kp; k0 += 32) {
#pragma unroll
        for (int i = 0; i < 6; ++i) {
            load_lds16(gp[i], &lds[loff[i]]);
            gp[i] += 32;
        }
        __syncthreads();

        bfrag8 ah[4], bh[4], bl[4];
#pragma unroll
        for (int t = 0; t < 4; ++t) {
            int ar = wm + t * 16 + fr;
            ah[t] = *(const bfrag8*)&lds[ar * 32 + fq];
            int br = wn + t * 16 + fr;
            bh[t] = *(const bfrag8*)&lds[4096 + br * 32 + fq];
            bl[t] = *(const bfrag8*)&lds[8192 + br * 32 + fq];
        }
#pragma unroll
        for (int i = 0; i < 4; ++i)
#pragma unroll
            for (int j = 0; j < 4; ++j) {
                acc[i][j] = MFMA16(ah[i], bh[j], acc[i][j]);
                acc[i][j] = MFMA16(ah[i], bl[j], acc[i][j]);
            }
        __syncthreads();
    }

    // epilogue: C/D layout col=lane&15, row=(lane>>4)*4+reg
#pragma unroll
    for (int i = 0; i < 4; ++i)
#pragma unroll
        for (int j = 0; j < 4; ++j) {
            int col = n0 + wn + j * 16 + (lane & 15);
            if (col >= N) continue;
            float bv = bias[col];
#pragma unroll
            for (int r = 0; r < 4; ++r) {
                int row = m0 + wm + i * 16 + (lane >> 4) * 4 + r;
                if (row < M)
                    C[(size_t)row * N + col] = acc[i][j][r] + bv;
            }
        }

    if (stats != nullptr) {
#pragma unroll
        for (int j = 0; j < 4; ++j) {
            int col = n0 + wn + j * 16 + (lane & 15);
            float cs = 0.f, cq = 0.f;
            if (col < N) {
                float bv = bias[col];
#pragma unroll
                for (int i = 0; i < 4; ++i)
#pragma unroll
                    for (int r = 0; r < 4; ++r) {
                        int row = m0 + wm + i * 16 + (lane >> 4) * 4 + r;
                        if (row < M) {
                            float y = acc[i][j][r] + bv;
                            cs += y;
                            cq = fmaf(y, y, cq);
                        }
                    }
            }
            cs += __shfl_xor(cs, 16, 64); cq += __shfl_xor(cq, 16, 64);
            cs += __shfl_xor(cs, 32, 64); cq += __shfl_xor(cq, 32, 64);
            if ((lane >> 4) == 0 && col < N) {
                atomicAdd(&stats[col], cs);
                atomicAdd(&stats[N + col], cq);
            }
        }
    }
}

// ---------------------------------------------------------------------------
// bf16 MFMA GEMM, A fp32 with fused BN-affine+ReLU applied during staging
// (abn = [a K | b K], y = relu(x*a+b)) -> bf16 hi only. Grid transposed as
// gemm_pp (x=N-block) for A L2 reuse. Column-stat epilogue for BN2.
// ---------------------------------------------------------------------------
__global__ __launch_bounds__(256, 2) void gemm_af(
    const float* __restrict__ A, const unsigned short* __restrict__ Bth,
    const unsigned short* __restrict__ Btl, const float* __restrict__ bias,
    float* __restrict__ C, int M, int N, int K, int Kp,
    const float* __restrict__ abn, float* __restrict__ stats)
{
    __shared__ unsigned short lds[12288];
    const int tid = threadIdx.x;
    const int lane = tid & 63;
    const int w = tid >> 6;
    const int m0 = blockIdx.y * 128;
    const int n0 = blockIdx.x * 128;
    const int wm = (w & 1) * 64;
    const int wn = (w >> 1) * 64;

    const int srow = lane >> 2;
    const int scol = (lane & 3) * 8;

    const unsigned short* gpb[4];
    unsigned loffb[4];
#pragma unroll
    for (int i = 0; i < 4; ++i) {
        int c = w * 4 + i;
        const unsigned short* pl = (c < 8) ? Bth : Btl;
        int rowg = n0 + (c & 7) * 16 + srow;
        gpb[i] = pl + (size_t)rowg * Kp + scol;
        loffb[i] = 4096 + c * 512;
    }

    facc4 acc[4][4];
    facc4 zero = {0.f, 0.f, 0.f, 0.f};
#pragma unroll
    for (int i = 0; i < 4; ++i)
#pragma unroll
        for (int j = 0; j < 4; ++j) acc[i][j] = zero;

    const int fr = lane & 15;
    const int fq = (lane >> 4) * 8;

    for (int k0 = 0; k0 < Kp; k0 += 32) {
#pragma unroll
        for (int i = 0; i < 4; ++i) {
            load_lds16(gpb[i], &lds[loffb[i]]);
            gpb[i] += 32;
        }
        // A fp32 -> BN affine + relu -> bf16 into LDS (128 rows x 32 k)
#pragma unroll
        for (int i = 0; i < 4; ++i) {
            int idx = tid + i * 256;
            int row = idx >> 3;
            int q4 = idx & 7;
            int rg = min(m0 + row, M - 1);
            int kk = k0 + q4 * 4;
            us4 h;
            if (kk < K) {
                float4 v = *(const float4*)&A[(size_t)rg * K + kk];
                float4 sa = *(const float4*)&abn[kk];
                float4 sb = *(const float4*)&abn[K + kk];
                h.x = f2bf(fmaxf(fmaf(v.x, sa.x, sb.x), 0.f));
                h.y = f2bf(fmaxf(fmaf(v.y, sa.y, sb.y), 0.f));
                h.z = f2bf(fmaxf(fmaf(v.z, sa.z, sb.z), 0.f));
                h.w = f2bf(fmaxf(fmaf(v.w, sa.w, sb.w), 0.f));
            } else {
                h.x = 0; h.y = 0; h.z = 0; h.w = 0;
            }
            *(us4*)&lds[row * 32 + q4 * 4] = h;
        }
        __syncthreads();

        bfrag8 ah[4], bh[4], bl[4];
#pragma unroll
        for (int t = 0; t < 4; ++t) {
            int ar = wm + t * 16 + fr;
            ah[t] = *(const bfrag8*)&lds[ar * 32 + fq];
            int br = wn + t * 16 + fr;
            bh[t] = *(const bfrag8*)&lds[4096 + br * 32 + fq];
            bl[t] = *(const bfrag8*)&lds[8192 + br * 32 + fq];
        }
#pragma unroll
        for (int i = 0; i < 4; ++i)
#pragma unroll
            for (int j = 0; j < 4; ++j) {
                acc[i][j] = MFMA16(ah[i], bh[j], acc[i][j]);
                acc[i][j] = MFMA16(ah[i], bl[j], acc[i][j]);
            }
        __syncthreads();
    }

#pragma unroll
    for (int i = 0; i < 4; ++i)
#pragma unroll
        for (int j = 0; j < 4; ++j) {
            int col = n0 + wn + j * 16 + (lane & 15);
            if (col >= N) continue;
            float bv = bias[col];
#pragma unroll
            for (int r = 0; r < 4; ++r) {
                int row = m0 + wm + i * 16 + (lane >> 4) * 4 + r;
                if (row < M)
                    C[(size_t)row * N + col] = acc[i][j][r] + bv;
            }
        }

    if (stats != nullptr) {
#pragma unroll
        for (int j = 0; j < 4; ++j) {
            int col = n0 + wn + j * 16 + (lane & 15);
            float cs = 0.f, cq = 0.f;
            if (col < N) {
                float bv = bias[col];
#pragma unroll
                for (int i = 0; i < 4; ++i)
#pragma unroll
                    for (int r = 0; r < 4; ++r) {
                        int row = m0 + wm + i * 16 + (lane >> 4) * 4 + r;
                        if (row < M) {
                            float y = acc[i][j][r] + bv;
                            cs += y;
                            cq = fmaf(y, y, cq);
                        }
                    }
            }
            cs += __shfl_xor(cs, 16, 64); cq += __shfl_xor(cq, 16, 64);
            cs += __shfl_xor(cs, 32, 64); cq += __shfl_xor(cq, 32, 64);
            if ((lane >> 4) == 0 && col < N) {
                atomicAdd(&stats[col], cs);
                atomicAdd(&stats[N + col], cq);
            }
        }
    }
}

// ---------------------------------------------------------------------------
// CSR build (dst-sorted). P[v] = end offset after fill.
// ---------------------------------------------------------------------------
__global__ __launch_bounds__(256) void csr_count(const int* __restrict__ dst, int* __restrict__ P)
{
    int e = blockIdx.x * 256 + threadIdx.x;
    if (e < N_EDGES) atomicAdd(&P[dst[e] + 1], 1);
}

__global__ __launch_bounds__(1024) void csr_scan(int* __restrict__ P)
{
    __shared__ int part[1024];
    const int t = threadIdx.x;
    const int CH = 49;
    int i0 = t * CH;
    int s = 0;
    for (int i = i0; i < i0 + CH; ++i) {
        if (i <= N_NODES) { s += P[i]; P[i] = s; }
    }
    part[t] = s;
    __syncthreads();
    if (t == 0) {
        int run = 0;
        for (int k = 0; k < 1024; ++k) { int tmp = part[k]; part[k] = run; run += tmp; }
    }
    __syncthreads();
    int off = part[t];
    for (int i = i0; i < i0 + CH; ++i) {
        if (i <= N_NODES) P[i] += off;
    }
}

__global__ __launch_bounds__(256) void csr_fill(
    const int* __restrict__ dst, int* __restrict__ P, int* __restrict__ eids)
{
    int e = blockIdx.x * 256 + threadIdx.x;
    if (e < N_EDGES) {
        int pos = atomicAdd(&P[dst[e]], 1);
        eids[pos] = e;
    }
}

// ---------------------------------------------------------------------------
// Re-sort src + edge_feat(->bf16) into CSR edge order. Runs once.
// ---------------------------------------------------------------------------
__global__ __launch_bounds__(256) void edge_pack_bf(
    const int* __restrict__ src, const int* __restrict__ eids,
    const float* __restrict__ edge_feat, int* __restrict__ es,
    unsigned short* __restrict__ efsb)
{
    int j = blockIdx.x * 256 + threadIdx.x;
    if (j >= N_EDGES) return;
    int e = eids[j];
    es[j] = src[e];
    const float* sp = edge_feat + (size_t)e * EFEAT;
    us8 o0, o1;
#pragma unroll
    for (int k = 0; k < 8; ++k) {
        o0[k] = f2bf(sp[k]);
        o1[k] = f2bf(sp[8 + k]);
    }
    *(us8*)&efsb[(size_t)j * EFEAT] = o0;
    *(us8*)&efsb[(size_t)j * EFEAT + 8] = o1;
}

// ---------------------------------------------------------------------------
// Gather aggregation v10 (MFMA + LDS-staged rows, pipelined).
// Block per NPB=16 nodes, 16-edge groups. Data motion redesigned from v9
// (which was latency-bound: 64B sliver reads, no overlap, 397us):
//  - the 16 gathered hn rows of a group are staged into LDS via async
//    global_load_lds with per-lane GLOBAL addresses walking each row
//    contiguously (per-wave ~1KB bursts -> DRAM-friendly), dest linear.
//  - double-buffered: stage(group g+1) issued BEFORE compute(group g);
//    one barrier per group drains the in-flight loads.
//  - edge weights (19 chunks hi/lo) live in per-wave REGISTERS (wave w owns
//    chunks 5w..5w+4), freeing LDS for the two row buffers (2x19712B).
//  - invalid edge slots stage from a -1e30 dummy row -> relu kills them,
//    no per-read masking. Empty nodes written in a pre-pass.
// LDS row stride 308 floats (1232B): ds_read hv is 2-way bank alias (free);
// row pad bytes 1200..1231 read past row end (in-workspace, discarded).
// ---------------------------------------------------------------------------
#define NPB 16

__global__ __launch_bounds__(256) void gather_mf(
    const float* __restrict__ hn, const unsigned short* __restrict__ efsb,
    const int* __restrict__ es, const int* __restrict__ P,
    const unsigned short* __restrict__ eWf, const float* __restrict__ dummy,
    unsigned short* __restrict__ aggH)
{
    __shared__ float ldsf[2][4928];      // 2 x (16 rows x 308 floats) = 39424 B
    const int tid = threadIdx.x;
    const int lane = tid & 63;
    const int w = tid >> 6;
    const int n15 = lane & 15;
    const int g = lane >> 4;

    // ---- per-wave weight fragments in registers (chunks 5w..5w+4) ----
    bfrag8 wbh[5], wbl[5];
#pragma unroll
    for (int i = 0; i < 5; ++i) {
        int c = 5 * w + i;
        int cc = (c < 19) ? c : 0;
        wbh[i] = *(const bfrag8*)&eWf[(size_t)(cc * 128 + lane) * 8];
        wbl[i] = *(const bfrag8*)&eWf[(size_t)(cc * 128 + 64 + lane) * 8];
    }

    const int v0 = blockIdx.x * NPB;
    const int vend = min(v0 + NPB, N_NODES);

    // ---- pre-pass: empty nodes get agg = hn directly (wave-strided) ----
    for (int ve = v0 + w; ve < vend; ve += 4) {
        int js = (ve == 0) ? 0 : P[ve - 1];
        int je = P[ve];
        if (js >= je) {
#pragma unroll
            for (int m = 0; m < 5; ++m) {
                int d = lane + 64 * m;
                float o = (d < DIM) ? hn[(size_t)ve * DIM + d] : 0.f;
                aggH[(size_t)ve * 320 + d] = f2bf(o);
            }
        }
    }

    // ---- find first nonempty node ----
    int v = v0, jb = 0, j1 = 0;
    {
        int jsp = (v0 == 0) ? 0 : P[v0 - 1];
        while (v < vend) {
            int je = P[v];
            if (jsp < je) { jb = jsp; j1 = je; break; }
            jsp = je;
            ++v;
        }
    }
    if (v >= vend) return;

    facc4 zero4 = {0.f, 0.f, 0.f, 0.f};
    facc4 acc[5];
#pragma unroll
    for (int i = 0; i < 5; ++i) acc[i] = zero4;

    // stage: 16 rows x 77 16B-chunks = 1232 chunks; 5 rounds of 256 lanes.
    // dest = linear (wave-uniform base + lane*16); src = per-lane row walk.
#define STAGE(SJB, SJ1, BSEL)                                              \
    {                                                                      \
        char* dst0 = (char*)&ldsf[BSEL][0];                                \
        _Pragma("unroll")                                                  \
        for (int rnd = 0; rnd < 5; ++rnd) {                                \
            int q = tid + rnd * 256;                                       \
            if (q < 1232) {                                                \
                int row = q / 77;                                          \
                int off = q - row * 77;                                    \
                int e = (SJB) + row;                                       \
                int s = es[min(e, N_EDGES - 1)];                           \
                const char* src = (e < (SJ1))                              \
                    ? (const char*)(hn + (size_t)s * DIM) + off * 16       \
                    : (const char*)dummy + off * 16;                       \
                load_lds16(src, dst0 + q * 16);                            \
            }                                                              \
        }                                                                  \
    }

    STAGE(jb, j1, 0);
    __syncthreads();
    int b = 0;

    while (true) {
        // ---- locate next group (uniform across block) ----
        int nv = v, njb = jb + 16, nj1 = j1;
        if (njb >= j1) {
            nv = v + 1;
            int jsp = j1;
            while (nv < vend) {
                int je = P[nv];
                if (jsp < je) { njb = jsp; nj1 = je; break; }
                jsp = je;
                ++nv;
            }
        }
        const bool more = (nv < vend);
        if (more) STAGE(njb, nj1, b ^ 1);

        // ---- compute current group from ldsf[b] ----
        bfrag8 af = {0, 0, 0, 0, 0, 0, 0, 0};
        if (g < 2) {
            int eA = min(jb + n15, N_EDGES - 1);
            af = *(const bfrag8*)&efsb[(size_t)eA * EFEAT + 8 * g];
        } else if (g == 2) {
            af[0] = (short)0x3F80;   // bf16 1.0 at k=16 (bias feature)
        }
        const float* hv0 = &ldsf[b][(g * 4) * 308 + n15];
#pragma unroll
        for (int i = 0; i < 5; ++i) {
            int c = 5 * w + i;
            if (c < 19) {            // wave-uniform (w==3 skips i==4)
                facc4 tt = MFMA16(af, wbl[i], zero4);
                tt = MFMA16(af, wbh[i], tt);
#pragma unroll
                for (int r = 0; r < 4; ++r) {
                    float hv = hv0[r * 308 + c * 16];
                    acc[i][r] += fmaxf(tt[r] + hv, 0.f);
                }
            }
        }

        // ---- node finished? reduce + write + reset ----
        if (jb + 16 >= j1) {
            float sred[5];
#pragma unroll
            for (int i = 0; i < 5; ++i) {
                float x = acc[i][0] + acc[i][1] + acc[i][2] + acc[i][3];
                x += __shfl_xor(x, 16, 64);
                x += __shfl_xor(x, 32, 64);
                sred[i] = x;
                acc[i] = zero4;
            }
#pragma unroll
            for (int i = 0; i < 5; ++i) {
                int c = 5 * w + i;
                if (c < 19 && g == (i & 3)) {
                    int d = c * 16 + n15;
                    float o = (d < DIM) ? sred[i] + hn[(size_t)v * DIM + d] : 0.f;
                    aggH[(size_t)v * 320 + d] = f2bf(o);
                }
            }
            if (w == 3 && g == 1)
                aggH[(size_t)v * 320 + 304 + n15] = 0;
        }

        __syncthreads();            // drains stage loads for buf b^1
        if (!more) break;
        b ^= 1;
        v = nv; jb = njb; j1 = nj1;
    }
#undef STAGE
}

// ---------------------------------------------------------------------------
// BN finalize + apply
// ---------------------------------------------------------------------------
__global__ __launch_bounds__(256) void bn_finalize(
    const float* __restrict__ stats, const float* __restrict__ g,
    const float* __restrict__ beta, float* __restrict__ ab, int C)
{
    int c = blockIdx.x * 256 + threadIdx.x;
    if (c >= C) return;
    const float invN = 1.f / (float)N_NODES;
    float m = stats[c] * invN;
    float v = stats[C + c] * invN - m * m;
    float a = g[c] * rsqrtf(v + BN_EPS);
    ab[c] = a;
    ab[C + c] = beta[c] - m * a;
}

__global__ __launch_bounds__(256) void bn_apply(
    const float* __restrict__ x, const float* __restrict__ ab,
    float* __restrict__ y, int total4, int C, int relu)
{
    int i = blockIdx.x * 256 + threadIdx.x;
    if (i >= total4) return;
    float4 v = ((const float4*)x)[i];
    int c = (i << 2) % C;
    const float* a = ab + c;
    const float* bb = ab + C + c;
    float4 r;
    r.x = fmaf(v.x, a[0], bb[0]);
    r.y = fmaf(v.y, a[1], bb[1]);
    r.z = fmaf(v.z, a[2], bb[2]);
    r.w = fmaf(v.w, a[3], bb[3]);
    if (relu) {
        r.x = fmaxf(r.x, 0.f); r.y = fmaxf(r.y, 0.f);
        r.z = fmaxf(r.z, 0.f); r.w = fmaxf(r.w, 0.f);
    }
    ((float4*)y)[i] = r;
}

// ---------------------------------------------------------------------------
// Mean pooling fused with last BN affine: hg = a*mean(h2)+b.
// ---------------------------------------------------------------------------
__global__ __launch_bounds__(256) void pool_seg_bn(
    const float* __restrict__ h2, const int* __restrict__ gid,
    const float* __restrict__ ab, float* __restrict__ hg)
{
    const int g = blockIdx.x;
    int lo = 0, hi = N_NODES;
    while (lo < hi) { int mid = (lo + hi) >> 1; if (gid[mid] < g) lo = mid + 1; else hi = mid; }
    int lo2 = lo, hi2 = N_NODES;
    while (lo2 < hi2) { int mid = (lo2 + hi2) >> 1; if (gid[mid] < g + 1) lo2 = mid + 1; else hi2 = mid; }
    const float inv = 1.f / fmaxf((float)(lo2 - lo), 1.f);
    for (int d = threadIdx.x; d < DIM; d += 256) {
        float s = 0.f;
        for (int r = lo; r < lo2; ++r) s += h2[(size_t)r * DIM + d];
        hg[(size_t)g * DIM + d] = fmaf(s * inv, ab[d], ab[DIM + d]);
    }
}

// fp32 tiled sgemm for the tiny prediction head
#define TS 64
#define BK 16
#define ASP 68

__global__ __launch_bounds__(256) void sgemm_bias(
    const float* __restrict__ A, const float* __restrict__ B,
    const float* __restrict__ bias, float* __restrict__ C,
    int M, int Ncol, int K)
{
    __shared__ float As[BK][ASP];
    __shared__ float Bs[BK][TS];
    const int tid = threadIdx.x;
    const int bm = blockIdx.x * TS;
    const int bn = blockIdx.y * TS;
    const int tm = (tid >> 4) * 4;
    const int tn = (tid & 15) * 4;
    float acc[4][4] = {};

    for (int k0 = 0; k0 < K; k0 += BK) {
#pragma unroll
        for (int i = 0; i < 4; ++i) {
            int idx = tid + i * 256;
            int m = idx >> 4;
            int k = idx & 15;
            int row = bm + m, kk = k0 + k;
            float v = 0.f;
            if (row < M && kk < K) v = A[(size_t)row * K + kk];
            As[k][m] = v;
        }
#pragma unroll
        for (int i = 0; i < 4; ++i) {
            int idx = tid + i * 256;
            int k = idx >> 6;
            int n = idx & 63;
            int col = bn + n, kk = k0 + k;
            float v = 0.f;
            if (col < Ncol && kk < K) v = B[(size_t)kk * Ncol + col];
            Bs[k][n] = v;
        }
        __syncthreads();
#pragma unroll
        for (int k = 0; k < BK; ++k) {
            float4 av = *(const float4*)&As[k][tm];
            float4 bv = *(const float4*)&Bs[k][tn];
            float a4[4] = {av.x, av.y, av.z, av.w};
            float b4[4] = {bv.x, bv.y, bv.z, bv.w};
#pragma unroll
            for (int i = 0; i < 4; ++i)
#pragma unroll
                for (int j = 0; j < 4; ++j)
                    acc[i][j] = fmaf(a4[i], b4[j], acc[i][j]);
        }
        __syncthreads();
    }

#pragma unroll
    for (int i = 0; i < 4; ++i) {
        int row = bm + tm + i;
        if (row >= M) continue;
#pragma unroll
        for (int j = 0; j < 4; ++j) {
            int col = bn + tn + j;
            if (col < Ncol)
                C[(size_t)row * Ncol + col] = acc[i][j] + bias[col];
        }
    }
}

// ---------------------------------------------------------------------------
extern "C" void kernel_launch(void* const* d_in, const int* in_sizes, int n_in,
                              void* d_out, int out_size, void* d_ws, size_t ws_size,
                              hipStream_t stream)
{
    const float* node_feat = (const float*)d_in[0];
    const float* edge_feat = (const float*)d_in[1];
    const int*   src       = (const int*)d_in[2];
    const int*   dst       = (const int*)d_in[3];
    const int*   gid       = (const int*)d_in[4];
    const float* node_W = (const float*)d_in[6];
    const float* node_b = (const float*)d_in[7];
    const float* edge_W = (const float*)d_in[8];
    const float* edge_b = (const float*)d_in[9];
    const float* W1  = (const float*)d_in[10];
    const float* b1  = (const float*)d_in[11];
    const float* g1  = (const float*)d_in[12];
    const float* be1 = (const float*)d_in[13];
    const float* W2  = (const float*)d_in[14];
    const float* b2  = (const float*)d_in[15];
    const float* g2  = (const float*)d_in[16];
    const float* be2 = (const float*)d_in[17];
    const float* pred_W = (const float*)d_in[18];
    const float* pred_b = (const float*)d_in[19];
    float* out = (float*)d_out;

    // ---- workspace layout (bytes), total < 248.73 MB (r9-proven) ----
    char* base = (char*)d_ws;
    float* hn            = (float*)(base + 0);                 // 60,000,000
    float* h2            = hn;                                 // in-place (hn dead after gather)
    float* x1            = (float*)(base + 60000000);          // 120,000,000
    unsigned short* nfH  = (unsigned short*)x1;                // alias (encoder only)
    unsigned short* aggH = (unsigned short*)(base + 180000000);// 32,000,000
    int*   es            = (int*)(base + 212000000);           // 3,200,000
    unsigned short* efsb = (unsigned short*)(base + 215200000);// 25,600,000 (ends 240,800,000)
    float* dummy         = (float*)(base + 243900000);         // 1,280 (-1e30 row; in efsb->wtH gap)
    unsigned short* wtH  = (unsigned short*)(base + 244000000);// <=466,944 (W2: 384x608x2)
    unsigned short* wtL  = (unsigned short*)(base + 244500000);// <=466,944 (ends 244,966,944)
    int*   eids          = (int*)(base + 245000000);           // 3,200,000
    unsigned short* eWf  = (unsigned short*)(base + 245000000);// 38,912 (aliases eids, used after)
    int*   P             = (int*)(base + 248200000);           // 200,004
    float* stats         = (float*)(base + 248400016);
    float* ab            = (float*)(base + 248407216);
    float* hg            = (float*)(base + 248414416);         // 307,200
    float* stats2        = stats + 1200;
    float* ab2           = ab + 1200;

    dim3 blk(256);

    // ---- node encoder: hn = node_feat @ node_W + node_b ----
    tobf4<<<dim3((N_NODES * NFEAT / 4 + 255) / 256), blk, 0, stream>>>(
        node_feat, nfH, N_NODES * NFEAT / 4);
    conv_wt<<<dim3((384 * 128 + 255) / 256), blk, 0, stream>>>(
        node_W, wtH, wtL, NFEAT, DIM, 128, 384);
    gemm_pp<<<dim3(3, 391), blk, 0, stream>>>(
        nfH, wtH, wtL, node_b, hn, N_NODES, DIM, 128, nullptr);

    // ---- CSR by dst + packed edge streams (layer-invariant, run once) ----
    hipMemsetAsync(P, 0, (N_NODES + 1) * sizeof(int), stream);
    csr_count<<<dim3((N_EDGES + 255) / 256), blk, 0, stream>>>(dst, P);
    csr_scan<<<dim3(1), dim3(1024), 0, stream>>>(P);
    csr_fill<<<dim3((N_EDGES + 255) / 256), blk, 0, stream>>>(dst, P, eids);
    edge_pack_bf<<<dim3((N_EDGES + 255) / 256), blk, 0, stream>>>(
        src, eids, edge_feat, es, efsb);
    fill_dummy<<<dim3(2), blk, 0, stream>>>(dummy);

    for (int l = 0; l < N_LAYERS; ++l) {
        // aggH = bf16(hn + sum relu(hn[src] + he))  [N][320], he via MFMA
        conv_ew<<<dim3(10), blk, 0, stream>>>(
            edge_W + (size_t)l * EFEAT * DIM, edge_b + (size_t)l * DIM, eWf);
        gather_mf<<<dim3((N_NODES + NPB - 1) / NPB), blk, 0, stream>>>(
            hn, efsb, es, P, eWf, dummy, aggH);

        hipMemsetAsync(stats, 0, 1800 * sizeof(float), stream);

        // x1 = agg @ W1 + b1   [N, 600]  (+ BN1 stats in epilogue)
        conv_wt<<<dim3((640 * 320 + 255) / 256), blk, 0, stream>>>(
            W1 + (size_t)l * DIM * 2 * DIM, wtH, wtL, DIM, 2 * DIM, 320, 640);
        gemm_pp<<<dim3(5, 391), blk, 0, stream>>>(
            aggH, wtH, wtL, b1 + (size_t)l * 2 * DIM, x1,
            N_NODES, 2 * DIM, 320, stats);
        bn_finalize<<<dim3(3), blk, 0, stream>>>(
            stats, g1 + (size_t)l * 2 * DIM, be1 + (size_t)l * 2 * DIM, ab, 2 * DIM);

        // h2(=hn) = relu(bn1(x1)) @ W2 + b2  (BN1 fused in staging; BN2 stats)
        conv_wt<<<dim3((384 * 608 + 255) / 256), blk, 0, stream>>>(
            W2 + (size_t)l * 2 * DIM * DIM, wtH, wtL, 2 * DIM, DIM, 608, 384);
        gemm_af<<<dim3(3, 391), blk, 0, stream>>>(
            x1, wtH, wtL, b2 + (size_t)l * DIM, h2, N_NODES, DIM, 2 * DIM, 608,
            ab, stats2);
        bn_finalize<<<dim3(2), blk, 0, stream>>>(
            stats2, g2 + (size_t)l * DIM, be2 + (size_t)l * DIM, ab2, DIM);

        // hn = bn2(h2) + relu, in place — except last layer (fused into pool)
        if (l < N_LAYERS - 1)
            bn_apply<<<dim3((N_NODES * DIM / 4 + 255) / 256), blk, 0, stream>>>(
                h2, ab2, hn, N_NODES * DIM / 4, DIM, 1);
    }

    // ---- mean pool with fused last-BN affine + head ----
    pool_seg_bn<<<dim3(N_GRAPHS), blk, 0, stream>>>(h2, gid, ab2, hg);
    sgemm_bias<<<dim3((N_GRAPHS + 63) / 64, (OUTD + 63) / 64), blk, 0, stream>>>(
        hg, pred_W, pred_b, out, N_GRAPHS, OUTD, DIM);
}

// Round 5
// 1976.458 us; speedup vs baseline: 2.2549x; 1.1876x over previous
//
#include <hip/hip_runtime.h>

#define N_NODES 50000
#define N_EDGES 800000
#define N_GRAPHS 256
#define N_LAYERS 3
#define DIM 300
#define NFEAT 128
#define EFEAT 16
#define OUTD 128
#define BN_EPS 1e-5f

typedef __attribute__((ext_vector_type(8))) short bfrag8;   // 8 bf16 = 4 VGPR (MFMA A/B operand)
typedef __attribute__((ext_vector_type(4))) float facc4;    // MFMA C/D
typedef __attribute__((ext_vector_type(4))) unsigned short us4;
typedef __attribute__((ext_vector_type(8))) unsigned short us8;
typedef __attribute__((ext_vector_type(4))) unsigned int ui4;

// ---------------- bf16 helpers (RNE) + hi/lo split ----------------
__device__ __forceinline__ unsigned short f2bf(float f) {
    unsigned u = __float_as_uint(f);
    unsigned r = ((u >> 16) & 1u) + 0x7fffu;
    return (unsigned short)((u + r) >> 16);
}
__device__ __forceinline__ float bf2f(unsigned short h) {
    return __uint_as_float(((unsigned)h) << 16);
}
__device__ __forceinline__ void split2(float v, unsigned short& h, unsigned short& l) {
    h = f2bf(v);
    l = f2bf(v - bf2f(h));
}

// v_dot2_f32_bf16: 2 bf16 MACs per instruction. Guarded: if the builtin is
// unavailable the gather falls back to the byte-identical v7 FMA loop.
#if __has_builtin(__builtin_amdgcn_fdot2_f32_bf16)
#define GATHER_DOT2 1
typedef __attribute__((ext_vector_type(2))) __bf16 bf16x2_t;
__device__ __forceinline__ float dot2bf(unsigned a, unsigned b, float c) {
    return __builtin_amdgcn_fdot2_f32_bf16(
        __builtin_bit_cast(bf16x2_t, a), __builtin_bit_cast(bf16x2_t, b), c, false);
}
#else
#define GATHER_DOT2 0
#endif

// async global->LDS, 16B per lane. LDS dest = uniform base + lane*16 (HW rule).
__device__ __forceinline__ void load_lds16(const void* gsrc, void* ldsdst) {
    __builtin_amdgcn_global_load_lds(
        (const __attribute__((address_space(1))) unsigned int*)gsrc,
        (__attribute__((address_space(3))) unsigned int*)ldsdst,
        16, 0, 0);
}

#define MFMA16(a, b, c) __builtin_amdgcn_mfma_f32_16x16x32_bf16(a, b, c, 0, 0, 0)

// ---------------------------------------------------------------------------
// fp32 -> bf16 (hi only), vectorized
// ---------------------------------------------------------------------------
__global__ __launch_bounds__(256) void tobf4(
    const float* __restrict__ x, unsigned short* __restrict__ H, int n4)
{
    int i = blockIdx.x * 256 + threadIdx.x;
    if (i >= n4) return;
    float4 v = ((const float4*)x)[i];
    us4 h;
    h.x = f2bf(v.x); h.y = f2bf(v.y); h.z = f2bf(v.z); h.w = f2bf(v.w);
    ((us4*)H)[i] = h;
}

// ---------------------------------------------------------------------------
// weight conversion: W fp32 [K][N] -> transposed padded hi/lo planes [Np][Kp]
// ---------------------------------------------------------------------------
__global__ __launch_bounds__(256) void conv_wt(
    const float* __restrict__ W, unsigned short* __restrict__ H,
    unsigned short* __restrict__ L, int K, int N, int Kp, int Np)
{
    int idx = blockIdx.x * 256 + threadIdx.x;
    if (idx >= Np * Kp) return;
    int n = idx / Kp;
    int k = idx - n * Kp;
    float v = (n < N && k < K) ? W[(size_t)k * N + n] : 0.f;
    unsigned short h, l;
    split2(v, h, l);
    H[idx] = h;
    L[idx] = l;
}

// ---------------------------------------------------------------------------
// bf16 MFMA GEMM: A plain bf16 [M][Kp]; B transposed hi/lo planes [Np][Kp].
// acc = Ah*Bh + Ah*Bl (2 MFMA/tile). Block 128x128, BK=32, 4 waves 2x2.
// GRID: blockIdx.x = N-block (fast-varying) so consecutive blocks share the
// same A row-tile -> A L2 reuse across column blocks. blockIdx.y = M-block.
// LDS 24KB: A | Bh | Bl. Optional column-stat epilogue (BN).
// ---------------------------------------------------------------------------
__global__ __launch_bounds__(256, 2) void gemm_pp(
    const unsigned short* __restrict__ Ah,
    const unsigned short* __restrict__ Bth, const unsigned short* __restrict__ Btl,
    const float* __restrict__ bias, float* __restrict__ C,
    int M, int N, int Kp, float* __restrict__ stats)
{
    __shared__ unsigned short lds[12288];   // 24 KB
    const int tid = threadIdx.x;
    const int lane = tid & 63;
    const int w = tid >> 6;
    const int m0 = blockIdx.y * 128;
    const int n0 = blockIdx.x * 128;
    const int wm = (w & 1) * 64;
    const int wn = (w >> 1) * 64;

    const int srow = lane >> 2;
    const int scol = (lane & 3) * 8;

    const unsigned short* gp[6];
    unsigned loff[6];
#pragma unroll
    for (int i = 0; i < 6; ++i) {
        int c = w * 6 + i;
        const unsigned short* pl = (c < 8) ? Ah : (c < 16) ? Bth : Btl;
        int rowg;
        if (c < 8) {
            rowg = m0 + (c & 7) * 16 + srow;
            rowg = min(rowg, M - 1);
        } else {
            rowg = n0 + (c & 7) * 16 + srow;
        }
        gp[i] = pl + (size_t)rowg * Kp + scol;
        loff[i] = c * 512;
    }

    facc4 acc[4][4];
    facc4 zero = {0.f, 0.f, 0.f, 0.f};
#pragma unroll
    for (int i = 0; i < 4; ++i)
#pragma unroll
        for (int j = 0; j < 4; ++j) acc[i][j] = zero;

    const int fr = lane & 15;
    const int fq = (lane >> 4) * 8;

    for (int k0 = 0; k0 < Kp; k0 += 32) {
#pragma unroll
        for (int i = 0; i < 6; ++i) {
            load_lds16(gp[i], &lds[loff[i]]);
            gp[i] += 32;
        }
        __syncthreads();

        bfrag8 ah[4], bh[4], bl[4];
#pragma unroll
        for (int t = 0; t < 4; ++t) {
            int ar = wm + t * 16 + fr;
            ah[t] = *(const bfrag8*)&lds[ar * 32 + fq];
            int br = wn + t * 16 + fr;
            bh[t] = *(const bfrag8*)&lds[4096 + br * 32 + fq];
            bl[t] = *(const bfrag8*)&lds[8192 + br * 32 + fq];
        }
#pragma unroll
        for (int i = 0; i < 4; ++i)
#pragma unroll
            for (int j = 0; j < 4; ++j) {
                acc[i][j] = MFMA16(ah[i], bh[j], acc[i][j]);
                acc[i][j] = MFMA16(ah[i], bl[j], acc[i][j]);
            }
        __syncthreads();
    }

    // epilogue: C/D layout col=lane&15, row=(lane>>4)*4+reg
#pragma unroll
    for (int i = 0; i < 4; ++i)
#pragma unroll
        for (int j = 0; j < 4; ++j) {
            int col = n0 + wn + j * 16 + (lane & 15);
            if (col >= N) continue;
            float bv = bias[col];
#pragma unroll
            for (int r = 0; r < 4; ++r) {
                int row = m0 + wm + i * 16 + (lane >> 4) * 4 + r;
                if (row < M)
                    C[(size_t)row * N + col] = acc[i][j][r] + bv;
            }
        }

    if (stats != nullptr) {
#pragma unroll
        for (int j = 0; j < 4; ++j) {
            int col = n0 + wn + j * 16 + (lane & 15);
            float cs = 0.f, cq = 0.f;
            if (col < N) {
                float bv = bias[col];
#pragma unroll
                for (int i = 0; i < 4; ++i)
#pragma unroll
                    for (int r = 0; r < 4; ++r) {
                        int row = m0 + wm + i * 16 + (lane >> 4) * 4 + r;
                        if (row < M) {
                            float y = acc[i][j][r] + bv;
                            cs += y;
                            cq = fmaf(y, y, cq);
                        }
                    }
            }
            cs += __shfl_xor(cs, 16, 64); cq += __shfl_xor(cq, 16, 64);
            cs += __shfl_xor(cs, 32, 64); cq += __shfl_xor(cq, 32, 64);
            if ((lane >> 4) == 0 && col < N) {
                atomicAdd(&stats[col], cs);
                atomicAdd(&stats[N + col], cq);
            }
        }
    }
}

// ---------------------------------------------------------------------------
// bf16 MFMA GEMM, A fp32 with fused BN-affine+ReLU applied during staging
// (abn = [a K | b K], y = relu(x*a+b)) -> bf16 hi only. Grid transposed as
// gemm_pp (x=N-block) for A L2 reuse. Column-stat epilogue for BN2.
// ---------------------------------------------------------------------------
__global__ __launch_bounds__(256, 2) void gemm_af(
    const float* __restrict__ A, const unsigned short* __restrict__ Bth,
    const unsigned short* __restrict__ Btl, const float* __restrict__ bias,
    float* __restrict__ C, int M, int N, int K, int Kp,
    const float* __restrict__ abn, float* __restrict__ stats)
{
    __shared__ unsigned short lds[12288];
    const int tid = threadIdx.x;
    const int lane = tid & 63;
    const int w = tid >> 6;
    const int m0 = blockIdx.y * 128;
    const int n0 = blockIdx.x * 128;
    const int wm = (w & 1) * 64;
    const int wn = (w >> 1) * 64;

    const int srow = lane >> 2;
    const int scol = (lane & 3) * 8;

    const unsigned short* gpb[4];
    unsigned loffb[4];
#pragma unroll
    for (int i = 0; i < 4; ++i) {
        int c = w * 4 + i;
        const unsigned short* pl = (c < 8) ? Bth : Btl;
        int rowg = n0 + (c & 7) * 16 + srow;
        gpb[i] = pl + (size_t)rowg * Kp + scol;
        loffb[i] = 4096 + c * 512;
    }

    facc4 acc[4][4];
    facc4 zero = {0.f, 0.f, 0.f, 0.f};
#pragma unroll
    for (int i = 0; i < 4; ++i)
#pragma unroll
        for (int j = 0; j < 4; ++j) acc[i][j] = zero;

    const int fr = lane & 15;
    const int fq = (lane >> 4) * 8;

    for (int k0 = 0; k0 < Kp; k0 += 32) {
#pragma unroll
        for (int i = 0; i < 4; ++i) {
            load_lds16(gpb[i], &lds[loffb[i]]);
            gpb[i] += 32;
        }
        // A fp32 -> BN affine + relu -> bf16 into LDS (128 rows x 32 k)
#pragma unroll
        for (int i = 0; i < 4; ++i) {
            int idx = tid + i * 256;
            int row = idx >> 3;
            int q4 = idx & 7;
            int rg = min(m0 + row, M - 1);
            int kk = k0 + q4 * 4;
            us4 h;
            if (kk < K) {
                float4 v = *(const float4*)&A[(size_t)rg * K + kk];
                float4 sa = *(const float4*)&abn[kk];
                float4 sb = *(const float4*)&abn[K + kk];
                h.x = f2bf(fmaxf(fmaf(v.x, sa.x, sb.x), 0.f));
                h.y = f2bf(fmaxf(fmaf(v.y, sa.y, sb.y), 0.f));
                h.z = f2bf(fmaxf(fmaf(v.z, sa.z, sb.z), 0.f));
                h.w = f2bf(fmaxf(fmaf(v.w, sa.w, sb.w), 0.f));
            } else {
                h.x = 0; h.y = 0; h.z = 0; h.w = 0;
            }
            *(us4*)&lds[row * 32 + q4 * 4] = h;
        }
        __syncthreads();

        bfrag8 ah[4], bh[4], bl[4];
#pragma unroll
        for (int t = 0; t < 4; ++t) {
            int ar = wm + t * 16 + fr;
            ah[t] = *(const bfrag8*)&lds[ar * 32 + fq];
            int br = wn + t * 16 + fr;
            bh[t] = *(const bfrag8*)&lds[4096 + br * 32 + fq];
            bl[t] = *(const bfrag8*)&lds[8192 + br * 32 + fq];
        }
#pragma unroll
        for (int i = 0; i < 4; ++i)
#pragma unroll
            for (int j = 0; j < 4; ++j) {
                acc[i][j] = MFMA16(ah[i], bh[j], acc[i][j]);
                acc[i][j] = MFMA16(ah[i], bl[j], acc[i][j]);
            }
        __syncthreads();
    }

#pragma unroll
    for (int i = 0; i < 4; ++i)
#pragma unroll
        for (int j = 0; j < 4; ++j) {
            int col = n0 + wn + j * 16 + (lane & 15);
            if (col >= N) continue;
            float bv = bias[col];
#pragma unroll
            for (int r = 0; r < 4; ++r) {
                int row = m0 + wm + i * 16 + (lane >> 4) * 4 + r;
                if (row < M)
                    C[(size_t)row * N + col] = acc[i][j][r] + bv;
            }
        }

    if (stats != nullptr) {
#pragma unroll
        for (int j = 0; j < 4; ++j) {
            int col = n0 + wn + j * 16 + (lane & 15);
            float cs = 0.f, cq = 0.f;
            if (col < N) {
                float bv = bias[col];
#pragma unroll
                for (int i = 0; i < 4; ++i)
#pragma unroll
                    for (int r = 0; r < 4; ++r) {
                        int row = m0 + wm + i * 16 + (lane >> 4) * 4 + r;
                        if (row < M) {
                            float y = acc[i][j][r] + bv;
                            cs += y;
                            cq = fmaf(y, y, cq);
                        }
                    }
            }
            cs += __shfl_xor(cs, 16, 64); cq += __shfl_xor(cq, 16, 64);
            cs += __shfl_xor(cs, 32, 64); cq += __shfl_xor(cq, 32, 64);
            if ((lane >> 4) == 0 && col < N) {
                atomicAdd(&stats[col], cs);
                atomicAdd(&stats[N + col], cq);
            }
        }
    }
}

// ---------------------------------------------------------------------------
// CSR build (dst-sorted). P[v] = end offset after fill.
// ---------------------------------------------------------------------------
__global__ __launch_bounds__(256) void csr_count(const int* __restrict__ dst, int* __restrict__ P)
{
    int e = blockIdx.x * 256 + threadIdx.x;
    if (e < N_EDGES) atomicAdd(&P[dst[e] + 1], 1);
}

__global__ __launch_bounds__(1024) void csr_scan(int* __restrict__ P)
{
    __shared__ int part[1024];
    const int t = threadIdx.x;
    const int CH = 49;
    int i0 = t * CH;
    int s = 0;
    for (int i = i0; i < i0 + CH; ++i) {
        if (i <= N_NODES) { s += P[i]; P[i] = s; }
    }
    part[t] = s;
    __syncthreads();
    if (t == 0) {
        int run = 0;
        for (int k = 0; k < 1024; ++k) { int tmp = part[k]; part[k] = run; run += tmp; }
    }
    __syncthreads();
    int off = part[t];
    for (int i = i0; i < i0 + CH; ++i) {
        if (i <= N_NODES) P[i] += off;
    }
}

__global__ __launch_bounds__(256) void csr_fill(
    const int* __restrict__ dst, int* __restrict__ P, int* __restrict__ eids)
{
    int e = blockIdx.x * 256 + threadIdx.x;
    if (e < N_EDGES) {
        int pos = atomicAdd(&P[dst[e]], 1);
        eids[pos] = e;
    }
}

// ---------------------------------------------------------------------------
// Re-sort src + edge_feat(->bf16) into CSR edge order. Runs once.
// ---------------------------------------------------------------------------
__global__ __launch_bounds__(256) void edge_pack_bf(
    const int* __restrict__ src, const int* __restrict__ eids,
    const float* __restrict__ edge_feat, int* __restrict__ es,
    unsigned short* __restrict__ efsb)
{
    int j = blockIdx.x * 256 + threadIdx.x;
    if (j >= N_EDGES) return;
    int e = eids[j];
    es[j] = src[e];
    const float* sp = edge_feat + (size_t)e * EFEAT;
    us8 o0, o1;
#pragma unroll
    for (int k = 0; k < 8; ++k) {
        o0[k] = f2bf(sp[k]);
        o1[k] = f2bf(sp[8 + k]);
    }
    *(us8*)&efsb[(size_t)j * EFEAT] = o0;
    *(us8*)&efsb[(size_t)j * EFEAT + 8] = o1;
}

// ---------------------------------------------------------------------------
// Gather aggregation v11: v7 structure (r9-proven 224us/layer: ONE wave per
// node, compact-stride fp32 hn rows, x4 edge unroll = 20 outstanding row
// loads) with the ef@eW transform moved from 80 v_fma_f32 to 40
// v_dot2_f32_bf16 (2 MACs/inst, consumes packed bf16 ef pairs directly,
// deletes the 16 bf2f unpacks). Weights pre-packed bf16-hi pairs in 40 VGPR
// (vs 80 f32). v7 was VALUBusy=76% -> this halves the dominant VALU cost.
// Fallback (#else) is the byte-identical v7 fp32-weight FMA loop.
// Output bf16 [N][320].
// ---------------------------------------------------------------------------
__global__ __launch_bounds__(256) void gather_agg7(
    const float* __restrict__ hn, const unsigned short* __restrict__ efsb,
    const int* __restrict__ es, const int* __restrict__ P,
    const float* __restrict__ eW, const float* __restrict__ eb,
    unsigned short* __restrict__ aggH)
{
    const int v = blockIdx.x * 4 + (threadIdx.x >> 6);
    if (v >= N_NODES) return;
    const int lane = threadIdx.x & 63;

    float acc[5];
    float ebv[5];
#if GATHER_DOT2
    unsigned wpk[8][5];   // feature-pair p=(2p,2p+1), dim chunk c: packed bf16
#pragma unroll
    for (int c = 0; c < 5; ++c) {
        int d = lane + 64 * c;
        bool dv = d < DIM;
        acc[c] = dv ? hn[(size_t)v * DIM + d] : 0.f;
        ebv[c] = dv ? eb[d] : 0.f;
#pragma unroll
        for (int p = 0; p < 8; ++p) {
            unsigned short h0 = dv ? f2bf(eW[(2 * p) * DIM + d]) : (unsigned short)0;
            unsigned short h1 = dv ? f2bf(eW[(2 * p + 1) * DIM + d]) : (unsigned short)0;
            wpk[p][c] = (unsigned)h0 | ((unsigned)h1 << 16);
        }
    }
#else
    float wr[EFEAT][5];
#pragma unroll
    for (int c = 0; c < 5; ++c) {
        int d = lane + 64 * c;
        bool dv = d < DIM;
        acc[c] = dv ? hn[(size_t)v * DIM + d] : 0.f;
        ebv[c] = dv ? eb[d] : 0.f;
#pragma unroll
        for (int k = 0; k < EFEAT; ++k)
            wr[k][c] = dv ? eW[k * DIM + d] : 0.f;
    }
#endif

    const int j0 = (v == 0) ? 0 : P[v - 1];
    const int j1 = P[v];

    int j = j0;
    for (; j + 4 <= j1; j += 4) {
        int s0 = __builtin_amdgcn_readfirstlane(es[j]);
        int s1 = __builtin_amdgcn_readfirstlane(es[j + 1]);
        int s2 = __builtin_amdgcn_readfirstlane(es[j + 2]);
        int s3 = __builtin_amdgcn_readfirstlane(es[j + 3]);
        const float* __restrict__ h0 = hn + (size_t)s0 * DIM;
        const float* __restrict__ h1 = hn + (size_t)s1 * DIM;
        const float* __restrict__ h2p = hn + (size_t)s2 * DIM;
        const float* __restrict__ h3 = hn + (size_t)s3 * DIM;
        float hv[4][5];
#pragma unroll
        for (int c = 0; c < 5; ++c) {
            int d = lane + 64 * c;
            bool dv = d < DIM;
            hv[0][c] = dv ? h0[d] : 0.f;
            hv[1][c] = dv ? h1[d] : 0.f;
            hv[2][c] = dv ? h2p[d] : 0.f;
            hv[3][c] = dv ? h3[d] : 0.f;
        }
#if GATHER_DOT2
        ui4 pa[4][2];
#pragma unroll
        for (int u = 0; u < 4; ++u) {
            pa[u][0] = *(const ui4*)&efsb[(size_t)(j + u) * EFEAT];
            pa[u][1] = *(const ui4*)&efsb[(size_t)(j + u) * EFEAT + 8];
        }
#pragma unroll
        for (int u = 0; u < 4; ++u) {
#pragma unroll
            for (int c = 0; c < 5; ++c) {
                float he = ebv[c];
                he = dot2bf(pa[u][0][0], wpk[0][c], he);
                he = dot2bf(pa[u][0][1], wpk[1][c], he);
                he = dot2bf(pa[u][0][2], wpk[2][c], he);
                he = dot2bf(pa[u][0][3], wpk[3][c], he);
                he = dot2bf(pa[u][1][0], wpk[4][c], he);
                he = dot2bf(pa[u][1][1], wpk[5][c], he);
                he = dot2bf(pa[u][1][2], wpk[6][c], he);
                he = dot2bf(pa[u][1][3], wpk[7][c], he);
                acc[c] += fmaxf(hv[u][c] + he, 0.f);
            }
        }
#else
        us8 pk[4][2];
#pragma unroll
        for (int u = 0; u < 4; ++u) {
            pk[u][0] = *(const us8*)&efsb[(size_t)(j + u) * EFEAT];
            pk[u][1] = *(const us8*)&efsb[(size_t)(j + u) * EFEAT + 8];
        }
#pragma unroll
        for (int u = 0; u < 4; ++u) {
            float ef[EFEAT];
#pragma unroll
            for (int k = 0; k < 8; ++k) {
                ef[k] = bf2f(pk[u][0][k]);
                ef[8 + k] = bf2f(pk[u][1][k]);
            }
#pragma unroll
            for (int c = 0; c < 5; ++c) {
                float he = ebv[c];
#pragma unroll
                for (int k = 0; k < EFEAT; ++k) he = fmaf(ef[k], wr[k][c], he);
                acc[c] += fmaxf(hv[u][c] + he, 0.f);
            }
        }
#endif
    }
    for (; j < j1; ++j) {
        int s = __builtin_amdgcn_readfirstlane(es[j]);
        const float* __restrict__ hp = hn + (size_t)s * DIM;
        float hv[5];
#pragma unroll
        for (int c = 0; c < 5; ++c) {
            int d = lane + 64 * c;
            hv[c] = (d < DIM) ? hp[d] : 0.f;
        }
#if GATHER_DOT2
        ui4 p0 = *(const ui4*)&efsb[(size_t)j * EFEAT];
        ui4 p1 = *(const ui4*)&efsb[(size_t)j * EFEAT + 8];
#pragma unroll
        for (int c = 0; c < 5; ++c) {
            float he = ebv[c];
            he = dot2bf(p0[0], wpk[0][c], he);
            he = dot2bf(p0[1], wpk[1][c], he);
            he = dot2bf(p0[2], wpk[2][c], he);
            he = dot2bf(p0[3], wpk[3][c], he);
            he = dot2bf(p1[0], wpk[4][c], he);
            he = dot2bf(p1[1], wpk[5][c], he);
            he = dot2bf(p1[2], wpk[6][c], he);
            he = dot2bf(p1[3], wpk[7][c], he);
            acc[c] += fmaxf(hv[c] + he, 0.f);
        }
#else
        us8 p0 = *(const us8*)&efsb[(size_t)j * EFEAT];
        us8 p1 = *(const us8*)&efsb[(size_t)j * EFEAT + 8];
        float ef[EFEAT];
#pragma unroll
        for (int k = 0; k < 8; ++k) {
            ef[k] = bf2f(p0[k]);
            ef[8 + k] = bf2f(p1[k]);
        }
#pragma unroll
        for (int c = 0; c < 5; ++c) {
            float he = ebv[c];
#pragma unroll
            for (int k = 0; k < EFEAT; ++k) he = fmaf(ef[k], wr[k][c], he);
            acc[c] += fmaxf(hv[c] + he, 0.f);
        }
#endif
    }

#pragma unroll
    for (int c = 0; c < 5; ++c)
        aggH[(size_t)v * 320 + lane + 64 * c] = f2bf(acc[c]);
}

// ---------------------------------------------------------------------------
// BN finalize + apply
// ---------------------------------------------------------------------------
__global__ __launch_bounds__(256) void bn_finalize(
    const float* __restrict__ stats, const float* __restrict__ g,
    const float* __restrict__ beta, float* __restrict__ ab, int C)
{
    int c = blockIdx.x * 256 + threadIdx.x;
    if (c >= C) return;
    const float invN = 1.f / (float)N_NODES;
    float m = stats[c] * invN;
    float v = stats[C + c] * invN - m * m;
    float a = g[c] * rsqrtf(v + BN_EPS);
    ab[c] = a;
    ab[C + c] = beta[c] - m * a;
}

__global__ __launch_bounds__(256) void bn_apply(
    const float* __restrict__ x, const float* __restrict__ ab,
    float* __restrict__ y, int total4, int C, int relu)
{
    int i = blockIdx.x * 256 + threadIdx.x;
    if (i >= total4) return;
    float4 v = ((const float4*)x)[i];
    int c = (i << 2) % C;
    const float* a = ab + c;
    const float* bb = ab + C + c;
    float4 r;
    r.x = fmaf(v.x, a[0], bb[0]);
    r.y = fmaf(v.y, a[1], bb[1]);
    r.z = fmaf(v.z, a[2], bb[2]);
    r.w = fmaf(v.w, a[3], bb[3]);
    if (relu) {
        r.x = fmaxf(r.x, 0.f); r.y = fmaxf(r.y, 0.f);
        r.z = fmaxf(r.z, 0.f); r.w = fmaxf(r.w, 0.f);
    }
    ((float4*)y)[i] = r;
}

// ---------------------------------------------------------------------------
// Mean pooling fused with last BN affine: hg = a*mean(h2)+b.
// ---------------------------------------------------------------------------
__global__ __launch_bounds__(256) void pool_seg_bn(
    const float* __restrict__ h2, const int* __restrict__ gid,
    const float* __restrict__ ab, float* __restrict__ hg)
{
    const int g = blockIdx.x;
    int lo = 0, hi = N_NODES;
    while (lo < hi) { int mid = (lo + hi) >> 1; if (gid[mid] < g) lo = mid + 1; else hi = mid; }
    int lo2 = lo, hi2 = N_NODES;
    while (lo2 < hi2) { int mid = (lo2 + hi2) >> 1; if (gid[mid] < g + 1) lo2 = mid + 1; else hi2 = mid; }
    const float inv = 1.f / fmaxf((float)(lo2 - lo), 1.f);
    for (int d = threadIdx.x; d < DIM; d += 256) {
        float s = 0.f;
        for (int r = lo; r < lo2; ++r) s += h2[(size_t)r * DIM + d];
        hg[(size_t)g * DIM + d] = fmaf(s * inv, ab[d], ab[DIM + d]);
    }
}

// fp32 tiled sgemm for the tiny prediction head
#define TS 64
#define BK 16
#define ASP 68

__global__ __launch_bounds__(256) void sgemm_bias(
    const float* __restrict__ A, const float* __restrict__ B,
    const float* __restrict__ bias, float* __restrict__ C,
    int M, int Ncol, int K)
{
    __shared__ float As[BK][ASP];
    __shared__ float Bs[BK][TS];
    const int tid = threadIdx.x;
    const int bm = blockIdx.x * TS;
    const int bn = blockIdx.y * TS;
    const int tm = (tid >> 4) * 4;
    const int tn = (tid & 15) * 4;
    float acc[4][4] = {};

    for (int k0 = 0; k0 < K; k0 += BK) {
#pragma unroll
        for (int i = 0; i < 4; ++i) {
            int idx = tid + i * 256;
            int m = idx >> 4;
            int k = idx & 15;
            int row = bm + m, kk = k0 + k;
            float v = 0.f;
            if (row < M && kk < K) v = A[(size_t)row * K + kk];
            As[k][m] = v;
        }
#pragma unroll
        for (int i = 0; i < 4; ++i) {
            int idx = tid + i * 256;
            int k = idx >> 6;
            int n = idx & 63;
            int col = bn + n, kk = k0 + k;
            float v = 0.f;
            if (col < Ncol && kk < K) v = B[(size_t)kk * Ncol + col];
            Bs[k][n] = v;
        }
        __syncthreads();
#pragma unroll
        for (int k = 0; k < BK; ++k) {
            float4 av = *(const float4*)&As[k][tm];
            float4 bv = *(const float4*)&Bs[k][tn];
            float a4[4] = {av.x, av.y, av.z, av.w};
            float b4[4] = {bv.x, bv.y, bv.z, bv.w};
#pragma unroll
            for (int i = 0; i < 4; ++i)
#pragma unroll
                for (int j = 0; j < 4; ++j)
                    acc[i][j] = fmaf(a4[i], b4[j], acc[i][j]);
        }
        __syncthreads();
    }

#pragma unroll
    for (int i = 0; i < 4; ++i) {
        int row = bm + tm + i;
        if (row >= M) continue;
#pragma unroll
        for (int j = 0; j < 4; ++j) {
            int col = bn + tn + j;
            if (col < Ncol)
                C[(size_t)row * Ncol + col] = acc[i][j] + bias[col];
        }
    }
}

// ---------------------------------------------------------------------------
extern "C" void kernel_launch(void* const* d_in, const int* in_sizes, int n_in,
                              void* d_out, int out_size, void* d_ws, size_t ws_size,
                              hipStream_t stream)
{
    const float* node_feat = (const float*)d_in[0];
    const float* edge_feat = (const float*)d_in[1];
    const int*   src       = (const int*)d_in[2];
    const int*   dst       = (const int*)d_in[3];
    const int*   gid       = (const int*)d_in[4];
    const float* node_W = (const float*)d_in[6];
    const float* node_b = (const float*)d_in[7];
    const float* edge_W = (const float*)d_in[8];
    const float* edge_b = (const float*)d_in[9];
    const float* W1  = (const float*)d_in[10];
    const float* b1  = (const float*)d_in[11];
    const float* g1  = (const float*)d_in[12];
    const float* be1 = (const float*)d_in[13];
    const float* W2  = (const float*)d_in[14];
    const float* b2  = (const float*)d_in[15];
    const float* g2  = (const float*)d_in[16];
    const float* be2 = (const float*)d_in[17];
    const float* pred_W = (const float*)d_in[18];
    const float* pred_b = (const float*)d_in[19];
    float* out = (float*)d_out;

    // ---- workspace layout (bytes), total < 248.73 MB (r9-proven) ----
    char* base = (char*)d_ws;
    float* hn            = (float*)(base + 0);                 // 60,000,000
    float* h2            = hn;                                 // in-place (hn dead after gather)
    float* x1            = (float*)(base + 60000000);          // 120,000,000
    unsigned short* nfH  = (unsigned short*)x1;                // alias (encoder only)
    unsigned short* aggH = (unsigned short*)(base + 180000000);// 32,000,000
    int*   es            = (int*)(base + 212000000);           // 3,200,000
    unsigned short* efsb = (unsigned short*)(base + 215200000);// 25,600,000
    unsigned short* wtH  = (unsigned short*)(base + 244000000);
    unsigned short* wtL  = (unsigned short*)(base + 244500000);
    int*   eids          = (int*)(base + 245000000);           // 3,200,000
    int*   P             = (int*)(base + 248200000);           // 200,004
    float* stats         = (float*)(base + 248400016);
    float* ab            = (float*)(base + 248407216);
    float* hg            = (float*)(base + 248414416);         // 307,200
    float* stats2        = stats + 1200;
    float* ab2           = ab + 1200;

    dim3 blk(256);

    // ---- node encoder: hn = node_feat @ node_W + node_b ----
    tobf4<<<dim3((N_NODES * NFEAT / 4 + 255) / 256), blk, 0, stream>>>(
        node_feat, nfH, N_NODES * NFEAT / 4);
    conv_wt<<<dim3((384 * 128 + 255) / 256), blk, 0, stream>>>(
        node_W, wtH, wtL, NFEAT, DIM, 128, 384);
    gemm_pp<<<dim3(3, 391), blk, 0, stream>>>(
        nfH, wtH, wtL, node_b, hn, N_NODES, DIM, 128, nullptr);

    // ---- CSR by dst + packed edge streams (layer-invariant, run once) ----
    hipMemsetAsync(P, 0, (N_NODES + 1) * sizeof(int), stream);
    csr_count<<<dim3((N_EDGES + 255) / 256), blk, 0, stream>>>(dst, P);
    csr_scan<<<dim3(1), dim3(1024), 0, stream>>>(P);
    csr_fill<<<dim3((N_EDGES + 255) / 256), blk, 0, stream>>>(dst, P, eids);
    edge_pack_bf<<<dim3((N_EDGES + 255) / 256), blk, 0, stream>>>(
        src, eids, edge_feat, es, efsb);

    for (int l = 0; l < N_LAYERS; ++l) {
        // aggH = bf16(hn + sum relu(hn[src] + he))  [N][320]
        gather_agg7<<<dim3((N_NODES + 3) / 4), blk, 0, stream>>>(
            hn, efsb, es, P,
            edge_W + (size_t)l * EFEAT * DIM, edge_b + (size_t)l * DIM, aggH);

        hipMemsetAsync(stats, 0, 1800 * sizeof(float), stream);

        // x1 = agg @ W1 + b1   [N, 600]  (+ BN1 stats in epilogue)
        conv_wt<<<dim3((640 * 320 + 255) / 256), blk, 0, stream>>>(
            W1 + (size_t)l * DIM * 2 * DIM, wtH, wtL, DIM, 2 * DIM, 320, 640);
        gemm_pp<<<dim3(5, 391), blk, 0, stream>>>(
            aggH, wtH, wtL, b1 + (size_t)l * 2 * DIM, x1,
            N_NODES, 2 * DIM, 320, stats);
        bn_finalize<<<dim3(3), blk, 0, stream>>>(
            stats, g1 + (size_t)l * 2 * DIM, be1 + (size_t)l * 2 * DIM, ab, 2 * DIM);

        // h2(=hn) = relu(bn1(x1)) @ W2 + b2  (BN1 fused in staging; BN2 stats)
        conv_wt<<<dim3((384 * 608 + 255) / 256), blk, 0, stream>>>(
            W2 + (size_t)l * 2 * DIM * DIM, wtH, wtL, 2 * DIM, DIM, 608, 384);
        gemm_af<<<dim3(3, 391), blk, 0, stream>>>(
            x1, wtH, wtL, b2 + (size_t)l * DIM, h2, N_NODES, DIM, 2 * DIM, 608,
            ab, stats2);
        bn_finalize<<<dim3(2), blk, 0, stream>>>(
            stats2, g2 + (size_t)l * DIM, be2 + (size_t)l * DIM, ab2, DIM);

        // hn = bn2(h2) + relu, in place — except last layer (fused into pool)
        if (l < N_LAYERS - 1)
            bn_apply<<<dim3((N_NODES * DIM / 4 + 255) / 256), blk, 0, stream>>>(
                h2, ab2, hn, N_NODES * DIM / 4, DIM, 1);
    }

    // ---- mean pool with fused last-BN affine + head ----
    pool_seg_bn<<<dim3(N_GRAPHS), blk, 0, stream>>>(h2, gid, ab2, hg);
    sgemm_bias<<<dim3((N_GRAPHS + 63) / 64, (OUTD + 63) / 64), blk, 0, stream>>>(
        hg, pred_W, pred_b, out, N_GRAPHS, OUTD, DIM);
}